// Round 6
// baseline (597.157 us; speedup 1.0000x reference)
//
#include <hip/hip_runtime.h>
#include <stdint.h>

#define N_NODES 4096
#define F_IN    512
#define F_HID   256
#define F_CLS   16
#define NHEAD   4
#define ALPHA   0.2f
#define LOG2E   1.4426950408889634f

typedef __attribute__((ext_vector_type(8))) short short8;
typedef __attribute__((ext_vector_type(4))) float f32x4;

__device__ __forceinline__ float bf2f(unsigned short h) {
    unsigned u = ((unsigned)h) << 16; float f; __builtin_memcpy(&f, &u, 4); return f;
}
__device__ __forceinline__ unsigned short f2bf(float f) {
    unsigned u; __builtin_memcpy(&u, &f, 4);
    u += 0x7fffu + ((u >> 16) & 1u);
    return (unsigned short)(u >> 16);
}
__device__ __forceinline__ float lo_bf(unsigned u) { u <<= 16;          float f; __builtin_memcpy(&f,&u,4); return f; }
__device__ __forceinline__ float hi_bf(unsigned u) { u &= 0xffff0000u;  float f; __builtin_memcpy(&f,&u,4); return f; }

__device__ __forceinline__ void async_cp16(void* lds, const void* g) {
    __builtin_amdgcn_global_load_lds(
        (const __attribute__((address_space(1))) unsigned int*)g,
        (__attribute__((address_space(3))) unsigned int*)lds,
        16, 0, 0);
}

// s_waitcnt imm: vmcnt[3:0], expcnt[6:4]=7 (nowait), lgkmcnt[11:8]
__device__ __forceinline__ void pipe_barrier_vm3() {
    __builtin_amdgcn_sched_barrier(0);
    __builtin_amdgcn_s_waitcnt(0x0073);   // vmcnt(3) lgkmcnt(0)
    __builtin_amdgcn_s_barrier();
    __builtin_amdgcn_sched_barrier(0);
}
__device__ __forceinline__ void pipe_barrier_vm4() {
    __builtin_amdgcn_sched_barrier(0);
    __builtin_amdgcn_s_waitcnt(0x0074);   // vmcnt(4) lgkmcnt(0)
    __builtin_amdgcn_s_barrier();
    __builtin_amdgcn_sched_barrier(0);
}

// ============ K1: fused prep: adj->bitmask | fp32->bf16 converts | zero es1/ed1 ============
#define PREP_BM_BLOCKS   16384
#define PREP_CV_BLOCKS   1296
#define PREP_Z_BLOCKS    4
__global__ __launch_bounds__(256) void k_prep(const int* __restrict__ adj,
                                              const float* __restrict__ x,
                                              const float* __restrict__ W1,
                                              const float* __restrict__ W2,
                                              unsigned long long* __restrict__ bm,
                                              unsigned short* __restrict__ xb,
                                              unsigned short* __restrict__ W1t,
                                              float* __restrict__ W2t,
                                              float* __restrict__ ez) {
    int b = blockIdx.x;
    if (b < PREP_BM_BLOCKS) {
        int wv = threadIdx.x >> 6, lane = threadIdx.x & 63;
        int idx0 = b * 1024 + wv * 256;
        const int* p = adj + idx0 + lane;
        unsigned long long m0 = __ballot(p[0]   > 0);
        unsigned long long m1 = __ballot(p[64]  > 0);
        unsigned long long m2 = __ballot(p[128] > 0);
        unsigned long long m3 = __ballot(p[192] > 0);
        if (lane == 0) {
            int w = idx0 >> 6;
            bm[w] = m0; bm[w+1] = m1; bm[w+2] = m2; bm[w+3] = m3;
        }
        return;
    }
    if (b < PREP_BM_BLOCKS + PREP_CV_BLOCKS) {
        int tid = (b - PREP_BM_BLOCKS) * 256 + threadIdx.x;
        const int NXV = (N_NODES * F_IN) / 8;       // 262144
        const int NW1 = NHEAD * 64 * F_HID;         // 65536
        if (tid < NXV) {
            float4 a = *(const float4*)&x[tid * 8];
            float4 c = *(const float4*)&x[tid * 8 + 4];
            uint4 w;
            w.x = (unsigned)f2bf(a.x) | ((unsigned)f2bf(a.y) << 16);
            w.y = (unsigned)f2bf(a.z) | ((unsigned)f2bf(a.w) << 16);
            w.z = (unsigned)f2bf(c.x) | ((unsigned)f2bf(c.y) << 16);
            w.w = (unsigned)f2bf(c.z) | ((unsigned)f2bf(c.w) << 16);
            *(uint4*)&xb[tid * 8] = w;
        } else if (tid < NXV + NW1) {
            int j = tid - NXV;
            int o = j & 255, f8 = (j >> 8) & 63, h = j >> 14;
            float v[8];
            #pragma unroll
            for (int k = 0; k < 8; ++k)
                v[k] = W1[(size_t)(h * F_IN + f8 * 8 + k) * F_HID + o];
            uint4 w;
            w.x = (unsigned)f2bf(v[0]) | ((unsigned)f2bf(v[1]) << 16);
            w.y = (unsigned)f2bf(v[2]) | ((unsigned)f2bf(v[3]) << 16);
            w.z = (unsigned)f2bf(v[4]) | ((unsigned)f2bf(v[5]) << 16);
            w.w = (unsigned)f2bf(v[6]) | ((unsigned)f2bf(v[7]) << 16);
            *(uint4*)&W1t[(size_t)(h * F_HID + o) * F_IN + f8 * 8] = w;
        } else {
            int j = tid - NXV - NW1;
            if (j < F_HID * F_CLS) {
                int o = j >> 4, c = j & 15;
                W2t[c * F_HID + o] = W2[j];
            }
        }
        return;
    }
    {
        int zb = b - PREP_BM_BLOCKS - PREP_CV_BLOCKS;
        float4* z4 = (float4*)ez;
        #pragma unroll
        for (int r = 0; r < 8; ++r)
            z4[zb * 2048 + r * 256 + threadIdx.x] = make_float4(0.f, 0.f, 0.f, 0.f);
    }
}

// ============ K2: h1t[h][o][n] GEMM + fused e1 — triple-buffer pipeline ============
__global__ __launch_bounds__(256, 4) void k_gemm1(const unsigned short* __restrict__ xb,
                                                  const unsigned short* __restrict__ W1t,
                                                  const float* __restrict__ a1,
                                                  unsigned short* __restrict__ h1t,
                                                  float* __restrict__ es1,
                                                  float* __restrict__ ed1) {
    __shared__ unsigned short Sld[3][6144];
    const int t = threadIdx.x;
    const int lane = t & 63, wv = t >> 6, quad = lane >> 4, l15 = lane & 15;
    const int wn = wv & 1, wo = wv >> 1;
    const int n0 = blockIdx.x * 128;
    const int oo0 = blockIdx.y * 64;
    const int h = blockIdx.z;
    const int kl = (lane >> 4) * 8;

    const unsigned short* gs[3];
    int loff[3];
    #pragma unroll
    for (int s = 0; s < 3; ++s) {
        int c = wv * 3 + s;
        loff[s] = c * 512;
        gs[s] = (c < 8)
            ? (xb  + (size_t)(n0 + c * 16 + l15) * F_IN + kl)
            : (W1t + (size_t)(h * F_HID + oo0 + (c - 8) * 16 + l15) * F_IN + kl);
    }
    #pragma unroll
    for (int s = 0; s < 3; ++s) async_cp16(&Sld[0][loff[s]], gs[s]);
    #pragma unroll
    for (int s = 0; s < 3; ++s) async_cp16(&Sld[1][loff[s]], gs[s] + 32);

    f32x4 acc[4][2] = {};
    int cur = 0;
    for (int it = 0; it < 16; ++it) {
        pipe_barrier_vm3();
        {
            const int nxt = (cur >= 1) ? cur - 1 : 2;
            const int off = ((it + 2) & 15) * 32;
            #pragma unroll
            for (int s = 0; s < 3; ++s) async_cp16(&Sld[nxt][loff[s]], gs[s] + off);
        }
        short8 bfw[2];
        #pragma unroll
        for (int mi = 0; mi < 2; ++mi)
            bfw[mi] = *(const short8*)&Sld[cur][(8 + wo * 2 + mi) * 512 + lane * 8];
        #pragma unroll
        for (int ni = 0; ni < 4; ++ni) {
            short8 af = *(const short8*)&Sld[cur][(wn * 4 + ni) * 512 + lane * 8];
            #pragma unroll
            for (int mi = 0; mi < 2; ++mi)
                acc[ni][mi] = __builtin_amdgcn_mfma_f32_16x16x32_bf16(af, bfw[mi], acc[ni][mi], 0, 0, 0);
        }
        cur = (cur == 2) ? 0 : cur + 1;
    }
    #pragma unroll
    for (int ni = 0; ni < 4; ++ni)
      #pragma unroll
      for (int mi = 0; mi < 2; ++mi) {
        int o = oo0 + wo * 32 + mi * 16 + l15;
        int nb = n0 + wn * 64 + ni * 16 + quad * 4;
        uint2 uu;
        uu.x = (unsigned)f2bf(acc[ni][mi][0]) | ((unsigned)f2bf(acc[ni][mi][1]) << 16);
        uu.y = (unsigned)f2bf(acc[ni][mi][2]) | ((unsigned)f2bf(acc[ni][mi][3]) << 16);
        *(uint2*)&h1t[(size_t)(h * F_HID + o) * N_NODES + nb] = uu;
      }
    float a1s[2], a1d[2];
    #pragma unroll
    for (int mi = 0; mi < 2; ++mi) {
        int o = oo0 + wo * 32 + mi * 16 + l15;
        a1s[mi] = a1[h * 2 * F_HID + o] * LOG2E;
        a1d[mi] = a1[h * 2 * F_HID + F_HID + o] * LOG2E;
    }
    #pragma unroll
    for (int ni = 0; ni < 4; ++ni) {
        #pragma unroll
        for (int rg = 0; rg < 4; ++rg) {
            float es = acc[ni][0][rg] * a1s[0] + acc[ni][1][rg] * a1s[1];
            float ed = acc[ni][0][rg] * a1d[0] + acc[ni][1][rg] * a1d[1];
            #pragma unroll
            for (int off = 1; off < 16; off <<= 1) {
                es += __shfl_xor(es, off, 64);
                ed += __shfl_xor(ed, off, 64);
            }
            if (l15 == 0) {
                int n = n0 + wn * 64 + ni * 16 + quad * 4 + rg;
                atomicAdd(&es1[h * N_NODES + n], es);
                atomicAdd(&ed1[h * N_NODES + n], ed);
            }
        }
    }
}

// ============ K3: fused masked-softmax-GEMM layer 1 ============
// BM=64 (4 waves: 2 m-quarters x 2 o-halves), o=256, ksplit=4, grid(64,4,4)=1024 blocks.
// Register-pipelined bitmask (uint4/4-iters) + ed (1-iter lead); 3-stage LDS DMA.
__global__ __launch_bounds__(256, 3) void k_attn1(const unsigned short* __restrict__ h1t,
                                                  const float* __restrict__ es1,
                                                  const float* __restrict__ ed1,
                                                  const unsigned char* __restrict__ bmb,
                                                  unsigned short* __restrict__ C1p,
                                                  float* __restrict__ l1p) {
    __shared__ unsigned short Bld[3][8192];   // 3 x 16 KB, frag order
    const int t = threadIdx.x;
    const int lane = t & 63, wv = t >> 6, quad = lane >> 4, l15 = lane & 15;
    const int wo = wv & 1, wm = wv >> 1;
    const int m0 = blockIdx.x * 64;
    const int h = blockIdx.y;
    const int kz = blockIdx.z;
    const int mb0 = kz * 1024;

    const int m_r0 = m0 + wm * 32 + l15;
    const int m_r1 = m_r0 + 16;
    const float esr0 = es1[h * N_NODES + m_r0];   // pre-scaled by log2e
    const float esr1 = es1[h * N_NODES + m_r1];
    const unsigned char* bp0 = bmb + (size_t)m_r0 * (N_NODES / 8) + (mb0 >> 3);
    const unsigned char* bp1 = bmb + (size_t)m_r1 * (N_NODES / 8) + (mb0 >> 3);
    const float* edb = ed1 + h * N_NODES + mb0;

    // staging: wave stages chunks wv*4+s (16 o-tiles total), frag-order per-lane addrs
    const unsigned short* gs[4];
    int loff[4];
    #pragma unroll
    for (int s = 0; s < 4; ++s) {
        int c = wv * 4 + s;
        loff[s] = c * 512;
        gs[s] = h1t + (size_t)(h * F_HID + c * 16 + l15) * N_NODES + mb0 + quad * 8;
    }
    #pragma unroll
    for (int s = 0; s < 4; ++s) async_cp16(&Bld[0][loff[s]], gs[s]);
    #pragma unroll
    for (int s = 0; s < 4; ++s) async_cp16(&Bld[1][loff[s]], gs[s] + 32);

    // register prologue (iteration 0 operands)
    uint4 bq0 = *(const uint4*)bp0;
    uint4 bq1 = *(const uint4*)bp1;
    float4 e0 = *(const float4*)&edb[quad * 8];
    float4 e1 = *(const float4*)&edb[quad * 8 + 4];

    f32x4 acc[8][2] = {};
    float lsum0 = 0.f, lsum1 = 0.f;
    int cur = 0;
    for (int it4 = 0; it4 < 8; ++it4) {
        uint4 nbq0, nbq1;
        #pragma unroll
        for (int sub = 0; sub < 4; ++sub) {
            const int it = it4 * 4 + sub;
            pipe_barrier_vm4();
            // register prefetch for it+1 (issued BEFORE the DMA so vmcnt FIFO keeps DMA distance)
            const int itn = (it + 1) & 31;
            float4 ne0 = *(const float4*)&edb[itn * 32 + quad * 8];
            float4 ne1 = *(const float4*)&edb[itn * 32 + quad * 8 + 4];
            if (sub == 0) {
                nbq0 = *(const uint4*)(bp0 + (it4 + 1) * 16);
                nbq1 = *(const uint4*)(bp1 + (it4 + 1) * 16);
            }
            // DMA prefetch iteration it+2
            {
                const int nxt = (cur >= 1) ? cur - 1 : 2;
                const int mbp = ((it + 2) & 31) * 32;
                #pragma unroll
                for (int s = 0; s < 4; ++s) async_cp16(&Bld[nxt][loff[s]], gs[s] + mbp);
            }
            // P from current registers
            const unsigned d0[4] = {bq0.x, bq0.y, bq0.z, bq0.w};
            const unsigned d1[4] = {bq1.x, bq1.y, bq1.z, bq1.w};
            unsigned bb0 = (d0[sub] >> (quad * 8)) & 0xffu;
            unsigned bb1 = (d1[sub] >> (quad * 8)) & 0xffu;
            float ev[8] = {e0.x, e0.y, e0.z, e0.w, e1.x, e1.y, e1.z, e1.w};
            unsigned up0[8], up1[8];
            #pragma unroll
            for (int j = 0; j < 8; ++j) {
                float s0 = esr0 + ev[j]; s0 = fmaxf(s0, ALPHA * s0);
                float p0 = ((bb0 >> j) & 1u) ? __builtin_amdgcn_exp2f(s0) : 0.f;
                unsigned u0; __builtin_memcpy(&u0, &p0, 4); u0 &= 0xffff0000u;
                float pt0; __builtin_memcpy(&pt0, &u0, 4);
                lsum0 += pt0; up0[j] = u0;
                float s1 = esr1 + ev[j]; s1 = fmaxf(s1, ALPHA * s1);
                float p1 = ((bb1 >> j) & 1u) ? __builtin_amdgcn_exp2f(s1) : 0.f;
                unsigned u1; __builtin_memcpy(&u1, &p1, 4); u1 &= 0xffff0000u;
                float pt1; __builtin_memcpy(&pt1, &u1, 4);
                lsum1 += pt1; up1[j] = u1;
            }
            int pk0[4], pk1[4];
            #pragma unroll
            for (int j = 0; j < 4; ++j) {
                pk0[j] = __builtin_amdgcn_perm(up0[2*j+1], up0[2*j], 0x07060302u);
                pk1[j] = __builtin_amdgcn_perm(up1[2*j+1], up1[2*j], 0x07060302u);
            }
            short8 bfrag0, bfrag1;
            __builtin_memcpy(&bfrag0, pk0, 16);
            __builtin_memcpy(&bfrag1, pk1, 16);
            #pragma unroll
            for (int ot = 0; ot < 8; ++ot) {
                short8 af = *(const short8*)&Bld[cur][(wo * 8 + ot) * 512 + lane * 8];
                acc[ot][0] = __builtin_amdgcn_mfma_f32_16x16x32_bf16(af, bfrag0, acc[ot][0], 0, 0, 0);
                acc[ot][1] = __builtin_amdgcn_mfma_f32_16x16x32_bf16(af, bfrag1, acc[ot][1], 0, 0, 0);
            }
            e0 = ne0; e1 = ne1;
            if (sub == 3) { bq0 = nbq0; bq1 = nbq1; }
            cur = (cur == 2) ? 0 : cur + 1;
        }
    }
    lsum0 += __shfl_xor(lsum0, 16, 64); lsum0 += __shfl_xor(lsum0, 32, 64);
    lsum1 += __shfl_xor(lsum1, 16, 64); lsum1 += __shfl_xor(lsum1, 32, 64);
    if (quad == 0 && wo == 0) {
        l1p[(size_t)(kz * NHEAD + h) * N_NODES + m_r0] = lsum0;
        l1p[(size_t)(kz * NHEAD + h) * N_NODES + m_r1] = lsum1;
    }
    unsigned short* Cb = C1p + (size_t)(kz * NHEAD + h) * N_NODES * F_HID;
    #pragma unroll
    for (int ot = 0; ot < 8; ++ot)
      #pragma unroll
      for (int mi = 0; mi < 2; ++mi) {
        int m = (mi == 0) ? m_r0 : m_r1;
        int o0 = wo * 128 + ot * 16 + quad * 4;
        uint2 uu;
        uu.x = (unsigned)f2bf(acc[ot][mi][0]) | ((unsigned)f2bf(acc[ot][mi][1]) << 16);
        uu.y = (unsigned)f2bf(acc[ot][mi][2]) | ((unsigned)f2bf(acc[ot][mi][3]) << 16);
        *(uint2*)&Cb[(size_t)m * F_HID + o0] = uu;
      }
}

// ============ K4: combine ksplit+heads, normalize, mean, relu -> h2 bf16 ============
__global__ __launch_bounds__(256) void k_reduce1(const unsigned short* __restrict__ C1p,
                                                 const float* __restrict__ l1p,
                                                 unsigned short* __restrict__ h2) {
    int t = threadIdx.x;
    int og = t & 31, nl = t >> 5;
    int n = blockIdx.x * 8 + nl;
    float acc8[8] = {};
    #pragma unroll
    for (int h = 0; h < NHEAD; ++h) {
        float den = 0.f, num[8] = {};
        #pragma unroll
        for (int kz = 0; kz < 4; ++kz) {
            den += l1p[(size_t)(kz * NHEAD + h) * N_NODES + n];
            uint4 u = *(const uint4*)&C1p[((size_t)(kz * NHEAD + h) * N_NODES + n) * F_HID + og * 8];
            num[0] += lo_bf(u.x); num[1] += hi_bf(u.x);
            num[2] += lo_bf(u.y); num[3] += hi_bf(u.y);
            num[4] += lo_bf(u.z); num[5] += hi_bf(u.z);
            num[6] += lo_bf(u.w); num[7] += hi_bf(u.w);
        }
        float rinv = 1.f / fmaxf(den, 1e-30f);
        #pragma unroll
        for (int j = 0; j < 8; ++j) acc8[j] += num[j] * rinv;
    }
    uint4 w;
    unsigned short bq[8];
    #pragma unroll
    for (int j = 0; j < 8; ++j) bq[j] = f2bf(fmaxf(acc8[j] * 0.25f, 0.f));
    w.x = (unsigned)bq[0] | ((unsigned)bq[1] << 16);
    w.y = (unsigned)bq[2] | ((unsigned)bq[3] << 16);
    w.z = (unsigned)bq[4] | ((unsigned)bq[5] << 16);
    w.w = (unsigned)bq[6] | ((unsigned)bq[7] << 16);
    *(uint4*)&h2[(size_t)n * F_HID + og * 8] = w;
}

// ============ K5: h2wt[c][n] = h2[n]·W2t[c], e_src2/e_dst2 (scaled by log2e) ============
__global__ __launch_bounds__(256) void k_h2w(const unsigned short* __restrict__ h2,
                                             const float* __restrict__ W2t,
                                             const float* __restrict__ a2,
                                             unsigned short* __restrict__ h2wt,
                                             float* __restrict__ es2, float* __restrict__ ed2) {
    int t = threadIdx.x;
    int c = t & 15, nl = t >> 4;
    int n = blockIdx.x * 16 + nl;
    const unsigned short* hrow = h2 + (size_t)n * F_HID;
    const float* wrow = W2t + c * F_HID;
    float dot = 0.f;
    for (int o = 0; o < F_HID; o += 8) {
        uint4 hu = *(const uint4*)&hrow[o];
        float4 w0 = *(const float4*)&wrow[o];
        float4 w1 = *(const float4*)&wrow[o + 4];
        dot += lo_bf(hu.x)*w0.x + hi_bf(hu.x)*w0.y + lo_bf(hu.y)*w0.z + hi_bf(hu.y)*w0.w;
        dot += lo_bf(hu.z)*w1.x + hi_bf(hu.z)*w1.y + lo_bf(hu.w)*w1.z + hi_bf(hu.w)*w1.w;
    }
    h2wt[(size_t)c * N_NODES + n] = f2bf(dot);
    float es = dot * a2[c] * LOG2E;
    float ed = dot * a2[F_CLS + c] * LOG2E;
    #pragma unroll
    for (int off = 1; off < 16; off <<= 1) {
        es += __shfl_xor(es, off, 64);
        ed += __shfl_xor(ed, off, 64);
    }
    if (c == 0) { es2[n] = es; ed2[n] = ed; }
}

// ============ K6: layer-2 fused softmax-GEMM — reg-pipelined, no LDS/barriers, ksplit=8 ============
__global__ __launch_bounds__(256, 4) void k_attn2(const unsigned short* __restrict__ h2wt,
                                                  const float* __restrict__ es2,
                                                  const float* __restrict__ ed2,
                                                  const unsigned char* __restrict__ bmb,
                                                  float* __restrict__ out2p,
                                                  float* __restrict__ l2p) {
    const int t = threadIdx.x;
    const int lane = t & 63, wv = t >> 6, quad = lane >> 4, l15 = lane & 15;
    const int m0 = blockIdx.x * 64;
    const int ks = blockIdx.y;
    const int mb0 = ks * 512;
    const int m_r = m0 + wv * 16 + l15;
    const float esr = es2[m_r];
    const unsigned char* bp = bmb + (size_t)m_r * (N_NODES / 8) + (mb0 >> 3);
    const float* edb = ed2 + mb0;
    const unsigned short* hb = h2wt + (size_t)l15 * N_NODES + mb0 + quad * 8;

    uint4 bq = *(const uint4*)bp;
    float4 e0 = *(const float4*)&edb[quad * 8];
    float4 e1 = *(const float4*)&edb[quad * 8 + 4];
    short8 bfr = *(const short8*)&hb[0];

    f32x4 acc = {};
    float lsum = 0.f;
    for (int it4 = 0; it4 < 4; ++it4) {
        uint4 nbq;
        #pragma unroll
        for (int sub = 0; sub < 4; ++sub) {
            const int it = it4 * 4 + sub;
            const int itn = (it + 1) & 15;
            float4 ne0 = *(const float4*)&edb[itn * 32 + quad * 8];
            float4 ne1 = *(const float4*)&edb[itn * 32 + quad * 8 + 4];
            short8 nbf = *(const short8*)&hb[itn * 32];
            if (sub == 0) nbq = *(const uint4*)(bp + (it4 + 1) * 16);
            const unsigned d[4] = {bq.x, bq.y, bq.z, bq.w};
            unsigned bb = (d[sub] >> (quad * 8)) & 0xffu;
            float ev[8] = {e0.x, e0.y, e0.z, e0.w, e1.x, e1.y, e1.z, e1.w};
            short8 afrag;
            #pragma unroll
            for (int j = 0; j < 8; ++j) {
                float s = esr + ev[j]; s = fmaxf(s, ALPHA * s);
                float p = ((bb >> j) & 1u) ? __builtin_amdgcn_exp2f(s) : 0.f;
                lsum += p; afrag[j] = (short)f2bf(p);
            }
            acc = __builtin_amdgcn_mfma_f32_16x16x32_bf16(afrag, bfr, acc, 0, 0, 0);
            e0 = ne0; e1 = ne1; bfr = nbf;
            if (sub == 3) bq = nbq;
        }
    }
    lsum += __shfl_xor(lsum, 16, 64); lsum += __shfl_xor(lsum, 32, 64);
    if (quad == 0) l2p[(size_t)ks * N_NODES + m_r] = lsum;
    #pragma unroll
    for (int rg = 0; rg < 4; ++rg) {
        int row = m0 + wv * 16 + quad * 4 + rg;
        out2p[((size_t)ks * N_NODES + row) * F_CLS + l15] = acc[rg];
    }
}

// ============ K7: combine ksplit, normalize, log_softmax -> fp32 ============
__global__ __launch_bounds__(256) void k_final(const float* __restrict__ out2p,
                                               const float* __restrict__ l2p,
                                               float* __restrict__ out) {
    int t = threadIdx.x;
    int c = t & 15, nl = t >> 4;
    int n = blockIdx.x * 16 + nl;
    float v = 0.f, l = 0.f;
    #pragma unroll
    for (int ks = 0; ks < 8; ++ks) {
        v += out2p[((size_t)ks * N_NODES + n) * F_CLS + c];
        l += l2p[(size_t)ks * N_NODES + n];
    }
    v /= fmaxf(l, 1e-30f);
    float mx = v;
    #pragma unroll
    for (int off = 1; off < 16; off <<= 1) mx = fmaxf(mx, __shfl_xor(mx, off, 64));
    float e = __expf(v - mx);
    float se = e;
    #pragma unroll
    for (int off = 1; off < 16; off <<= 1) se += __shfl_xor(se, off, 64);
    out[(size_t)n * F_CLS + c] = v - mx - __logf(se);
}

// ---------------- workspace layout (bytes) ----------------
#define OFF_BM    0ull                      // 2 MB   bitmask
#define OFF_XB    2097152ull                // 4 MB   x bf16
#define OFF_W1T   6291456ull                // 1 MB   W1t bf16
#define OFF_W2T   7340032ull                // 16 KB  W2t fp32
#define OFF_ES1   7356416ull                // 64 KB  (zeroed with ED1 in k_prep)
#define OFF_ED1   7421952ull                // 64 KB
#define OFF_ES2   7487488ull                // 16 KB
#define OFF_ED2   7503872ull                // 16 KB
#define OFF_L1P   7520256ull                // 256 KB [kz][h][n]
#define OFF_L2P   7782400ull                // 128 KB [ks][n]
#define OFF_H2    7910400ull                // 2 MB   bf16 (dead after k_h2w)
#define OFF_OUT2P 7910400ull                // 2 MB   fp32 — aliases H2
#define OFF_H2WT  10007552ull               // 128 KB bf16
#define OFF_H1T   10138624ull               // 8 MB   [h][o][n] bf16
#define OFF_C1P   18527232ull               // 16 MB  bf16 [kz][h][m][o]

extern "C" void kernel_launch(void* const* d_in, const int* in_sizes, int n_in,
                              void* d_out, int out_size, void* d_ws, size_t ws_size,
                              hipStream_t stream) {
    const float* x   = (const float*)d_in[0];
    const int*   adj = (const int*)d_in[1];
    const float* W1  = (const float*)d_in[2];
    const float* a1  = (const float*)d_in[3];
    const float* W2  = (const float*)d_in[4];
    const float* a2  = (const float*)d_in[5];
    float* out = (float*)d_out;
    char* ws = (char*)d_ws;

    unsigned long long* bm  = (unsigned long long*)(ws + OFF_BM);
    unsigned char*      bmb = (unsigned char*)(ws + OFF_BM);
    unsigned short* xb   = (unsigned short*)(ws + OFF_XB);
    unsigned short* W1t  = (unsigned short*)(ws + OFF_W1T);
    float* W2t   = (float*)(ws + OFF_W2T);
    float* es1   = (float*)(ws + OFF_ES1);
    float* ed1   = (float*)(ws + OFF_ED1);
    float* es2   = (float*)(ws + OFF_ES2);
    float* ed2   = (float*)(ws + OFF_ED2);
    float* l1p   = (float*)(ws + OFF_L1P);
    float* l2p   = (float*)(ws + OFF_L2P);
    unsigned short* h2   = (unsigned short*)(ws + OFF_H2);
    float* out2p = (float*)(ws + OFF_OUT2P);
    unsigned short* h2wt = (unsigned short*)(ws + OFF_H2WT);
    unsigned short* h1t  = (unsigned short*)(ws + OFF_H1T);
    unsigned short* C1p  = (unsigned short*)(ws + OFF_C1P);

    k_prep    <<<dim3(PREP_BM_BLOCKS + PREP_CV_BLOCKS + PREP_Z_BLOCKS), 256, 0, stream>>>(
                  adj, x, W1, W2, bm, xb, W1t, W2t, es1);
    k_gemm1   <<<dim3(32, 4, 4), 256, 0, stream>>>(xb, W1t, a1, h1t, es1, ed1);
    k_attn1   <<<dim3(64, 4, 4), 256, 0, stream>>>(h1t, es1, ed1, bmb, C1p, l1p);
    k_reduce1 <<<dim3(512),      256, 0, stream>>>(C1p, l1p, h2);
    k_h2w     <<<dim3(256),      256, 0, stream>>>(h2, W2t, a2, h2wt, es2, ed2);
    k_attn2   <<<dim3(64, 8),    256, 0, stream>>>(h2wt, es2, ed2, bmb, out2p, l2p);
    k_final   <<<dim3(256),      256, 0, stream>>>(out2p, l2p, out);
}

// Round 7
// 461.890 us; speedup vs baseline: 1.2929x; 1.2929x over previous
//
#include <hip/hip_runtime.h>
#include <stdint.h>

#define N_NODES 4096
#define F_IN    512
#define F_HID   256
#define F_CLS   16
#define NHEAD   4
#define ALPHA   0.2f
#define LOG2E   1.4426950408889634f

typedef __attribute__((ext_vector_type(8))) short short8;
typedef __attribute__((ext_vector_type(4))) float f32x4;

__device__ __forceinline__ float bf2f(unsigned short h) {
    unsigned u = ((unsigned)h) << 16; float f; __builtin_memcpy(&f, &u, 4); return f;
}
__device__ __forceinline__ unsigned short f2bf(float f) {
    unsigned u; __builtin_memcpy(&u, &f, 4);
    u += 0x7fffu + ((u >> 16) & 1u);
    return (unsigned short)(u >> 16);
}
__device__ __forceinline__ float lo_bf(unsigned u) { u <<= 16;          float f; __builtin_memcpy(&f,&u,4); return f; }
__device__ __forceinline__ float hi_bf(unsigned u) { u &= 0xffff0000u;  float f; __builtin_memcpy(&f,&u,4); return f; }

__device__ __forceinline__ void async_cp16(void* lds, const void* g) {
    __builtin_amdgcn_global_load_lds(
        (const __attribute__((address_space(1))) unsigned int*)g,
        (__attribute__((address_space(3))) unsigned int*)lds,
        16, 0, 0);
}

// s_waitcnt imm: vmcnt[3:0], expcnt[6:4]=7 (nowait), lgkmcnt[11:8]
__device__ __forceinline__ void pipe_barrier_vm2() {
    __builtin_amdgcn_sched_barrier(0);
    __builtin_amdgcn_s_waitcnt(0x0072);   // vmcnt(2) lgkmcnt(0)
    __builtin_amdgcn_s_barrier();
    __builtin_amdgcn_sched_barrier(0);
}
__device__ __forceinline__ void pipe_barrier_vm3() {
    __builtin_amdgcn_sched_barrier(0);
    __builtin_amdgcn_s_waitcnt(0x0073);   // vmcnt(3) lgkmcnt(0)
    __builtin_amdgcn_s_barrier();
    __builtin_amdgcn_sched_barrier(0);
}

// ============ K1: fused prep: adj->bitmask | fp32->bf16 converts | zero es1/ed1 ============
#define PREP_BM_BLOCKS   16384
#define PREP_CV_BLOCKS   1296
#define PREP_Z_BLOCKS    4
__global__ __launch_bounds__(256) void k_prep(const int* __restrict__ adj,
                                              const float* __restrict__ x,
                                              const float* __restrict__ W1,
                                              const float* __restrict__ W2,
                                              unsigned long long* __restrict__ bm,
                                              unsigned short* __restrict__ xb,
                                              unsigned short* __restrict__ W1t,
                                              float* __restrict__ W2t,
                                              float* __restrict__ ez) {
    int b = blockIdx.x;
    if (b < PREP_BM_BLOCKS) {
        int wv = threadIdx.x >> 6, lane = threadIdx.x & 63;
        int idx0 = b * 1024 + wv * 256;
        const int* p = adj + idx0 + lane;
        unsigned long long m0 = __ballot(p[0]   > 0);
        unsigned long long m1 = __ballot(p[64]  > 0);
        unsigned long long m2 = __ballot(p[128] > 0);
        unsigned long long m3 = __ballot(p[192] > 0);
        if (lane == 0) {
            int w = idx0 >> 6;
            bm[w] = m0; bm[w+1] = m1; bm[w+2] = m2; bm[w+3] = m3;
        }
        return;
    }
    if (b < PREP_BM_BLOCKS + PREP_CV_BLOCKS) {
        int tid = (b - PREP_BM_BLOCKS) * 256 + threadIdx.x;
        const int NXV = (N_NODES * F_IN) / 8;       // 262144
        const int NW1 = NHEAD * 64 * F_HID;         // 65536
        if (tid < NXV) {
            float4 a = *(const float4*)&x[tid * 8];
            float4 c = *(const float4*)&x[tid * 8 + 4];
            uint4 w;
            w.x = (unsigned)f2bf(a.x) | ((unsigned)f2bf(a.y) << 16);
            w.y = (unsigned)f2bf(a.z) | ((unsigned)f2bf(a.w) << 16);
            w.z = (unsigned)f2bf(c.x) | ((unsigned)f2bf(c.y) << 16);
            w.w = (unsigned)f2bf(c.z) | ((unsigned)f2bf(c.w) << 16);
            *(uint4*)&xb[tid * 8] = w;
        } else if (tid < NXV + NW1) {
            int j = tid - NXV;
            int o = j & 255, f8 = (j >> 8) & 63, h = j >> 14;
            float v[8];
            #pragma unroll
            for (int k = 0; k < 8; ++k)
                v[k] = W1[(size_t)(h * F_IN + f8 * 8 + k) * F_HID + o];
            uint4 w;
            w.x = (unsigned)f2bf(v[0]) | ((unsigned)f2bf(v[1]) << 16);
            w.y = (unsigned)f2bf(v[2]) | ((unsigned)f2bf(v[3]) << 16);
            w.z = (unsigned)f2bf(v[4]) | ((unsigned)f2bf(v[5]) << 16);
            w.w = (unsigned)f2bf(v[6]) | ((unsigned)f2bf(v[7]) << 16);
            *(uint4*)&W1t[(size_t)(h * F_HID + o) * F_IN + f8 * 8] = w;
        } else {
            int j = tid - NXV - NW1;
            if (j < F_HID * F_CLS) {
                int o = j >> 4, c = j & 15;
                W2t[c * F_HID + o] = W2[j];
            }
        }
        return;
    }
    {
        int zb = b - PREP_BM_BLOCKS - PREP_CV_BLOCKS;
        float4* z4 = (float4*)ez;
        #pragma unroll
        for (int r = 0; r < 8; ++r)
            z4[zb * 2048 + r * 256 + threadIdx.x] = make_float4(0.f, 0.f, 0.f, 0.f);
    }
}

// ============ K2: h1t[h][o][n] GEMM + fused e1 — triple-buffer pipeline ============
__global__ __launch_bounds__(256, 4) void k_gemm1(const unsigned short* __restrict__ xb,
                                                  const unsigned short* __restrict__ W1t,
                                                  const float* __restrict__ a1,
                                                  unsigned short* __restrict__ h1t,
                                                  float* __restrict__ es1,
                                                  float* __restrict__ ed1) {
    __shared__ unsigned short Sld[3][6144];
    const int t = threadIdx.x;
    const int lane = t & 63, wv = t >> 6, quad = lane >> 4, l15 = lane & 15;
    const int wn = wv & 1, wo = wv >> 1;
    const int n0 = blockIdx.x * 128;
    const int oo0 = blockIdx.y * 64;
    const int h = blockIdx.z;
    const int kl = (lane >> 4) * 8;

    const unsigned short* gs[3];
    int loff[3];
    #pragma unroll
    for (int s = 0; s < 3; ++s) {
        int c = wv * 3 + s;
        loff[s] = c * 512;
        gs[s] = (c < 8)
            ? (xb  + (size_t)(n0 + c * 16 + l15) * F_IN + kl)
            : (W1t + (size_t)(h * F_HID + oo0 + (c - 8) * 16 + l15) * F_IN + kl);
    }
    #pragma unroll
    for (int s = 0; s < 3; ++s) async_cp16(&Sld[0][loff[s]], gs[s]);
    #pragma unroll
    for (int s = 0; s < 3; ++s) async_cp16(&Sld[1][loff[s]], gs[s] + 32);

    f32x4 acc[4][2] = {};
    int cur = 0;
    for (int it = 0; it < 16; ++it) {
        pipe_barrier_vm3();
        {
            const int nxt = (cur >= 1) ? cur - 1 : 2;
            const int off = ((it + 2) & 15) * 32;
            #pragma unroll
            for (int s = 0; s < 3; ++s) async_cp16(&Sld[nxt][loff[s]], gs[s] + off);
        }
        short8 bfw[2];
        #pragma unroll
        for (int mi = 0; mi < 2; ++mi)
            bfw[mi] = *(const short8*)&Sld[cur][(8 + wo * 2 + mi) * 512 + lane * 8];
        #pragma unroll
        for (int ni = 0; ni < 4; ++ni) {
            short8 af = *(const short8*)&Sld[cur][(wn * 4 + ni) * 512 + lane * 8];
            #pragma unroll
            for (int mi = 0; mi < 2; ++mi)
                acc[ni][mi] = __builtin_amdgcn_mfma_f32_16x16x32_bf16(af, bfw[mi], acc[ni][mi], 0, 0, 0);
        }
        cur = (cur == 2) ? 0 : cur + 1;
    }
    #pragma unroll
    for (int ni = 0; ni < 4; ++ni)
      #pragma unroll
      for (int mi = 0; mi < 2; ++mi) {
        int o = oo0 + wo * 32 + mi * 16 + l15;
        int nb = n0 + wn * 64 + ni * 16 + quad * 4;
        uint2 uu;
        uu.x = (unsigned)f2bf(acc[ni][mi][0]) | ((unsigned)f2bf(acc[ni][mi][1]) << 16);
        uu.y = (unsigned)f2bf(acc[ni][mi][2]) | ((unsigned)f2bf(acc[ni][mi][3]) << 16);
        *(uint2*)&h1t[(size_t)(h * F_HID + o) * N_NODES + nb] = uu;
      }
    float a1s[2], a1d[2];
    #pragma unroll
    for (int mi = 0; mi < 2; ++mi) {
        int o = oo0 + wo * 32 + mi * 16 + l15;
        a1s[mi] = a1[h * 2 * F_HID + o] * LOG2E;
        a1d[mi] = a1[h * 2 * F_HID + F_HID + o] * LOG2E;
    }
    #pragma unroll
    for (int ni = 0; ni < 4; ++ni) {
        #pragma unroll
        for (int rg = 0; rg < 4; ++rg) {
            float es = acc[ni][0][rg] * a1s[0] + acc[ni][1][rg] * a1s[1];
            float ed = acc[ni][0][rg] * a1d[0] + acc[ni][1][rg] * a1d[1];
            #pragma unroll
            for (int off = 1; off < 16; off <<= 1) {
                es += __shfl_xor(es, off, 64);
                ed += __shfl_xor(ed, off, 64);
            }
            if (l15 == 0) {
                int n = n0 + wn * 64 + ni * 16 + quad * 4 + rg;
                atomicAdd(&es1[h * N_NODES + n], es);
                atomicAdd(&ed1[h * N_NODES + n], ed);
            }
        }
    }
}

// ============ K3: fused masked-softmax-GEMM layer 1 ============
// ROUND-5 TILING (BM=256, 8 waves x 32 m, o=256/wave, grid (16,4,4) — 128 MB total
// h1t re-read, L2-absorbable) + ROUND-6 REGISTER PIPELINING of bitmask/ed operands.
__global__ __launch_bounds__(512, 2) void k_attn1(const unsigned short* __restrict__ h1t,
                                                  const float* __restrict__ es1,
                                                  const float* __restrict__ ed1,
                                                  const unsigned char* __restrict__ bmb,
                                                  unsigned short* __restrict__ C1p,
                                                  float* __restrict__ l1p) {
    __shared__ unsigned short Bld[3][8192];   // 3 x 16 KB, frag order
    const int t = threadIdx.x;
    const int lane = t & 63, wv = t >> 6, quad = lane >> 4, l15 = lane & 15;
    const int m0 = blockIdx.x * 256;
    const int h = blockIdx.y;
    const int kz = blockIdx.z;
    const int mb0 = kz * 1024;

    const int m_r0 = m0 + wv * 32 + l15;
    const int m_r1 = m_r0 + 16;
    const float esr0 = es1[h * N_NODES + m_r0];   // pre-scaled by log2e
    const float esr1 = es1[h * N_NODES + m_r1];
    const unsigned char* bp0 = bmb + (size_t)m_r0 * (N_NODES / 8) + (mb0 >> 3);
    const unsigned char* bp1 = bmb + (size_t)m_r1 * (N_NODES / 8) + (mb0 >> 3);
    const float* edb = ed1 + h * N_NODES + mb0;

    // DMA: wave wv stages o-tile chunks wv and wv+8, frag-order per-lane addrs
    const unsigned short* gb0 = h1t + (size_t)(h * F_HID + wv * 16 + l15) * N_NODES + mb0 + quad * 8;
    const unsigned short* gb1 = h1t + (size_t)(h * F_HID + (wv + 8) * 16 + l15) * N_NODES + mb0 + quad * 8;
    async_cp16(&Bld[0][wv * 512], gb0);
    async_cp16(&Bld[0][(wv + 8) * 512], gb1);
    async_cp16(&Bld[1][wv * 512], gb0 + 32);
    async_cp16(&Bld[1][(wv + 8) * 512], gb1 + 32);

    // register prologue (iteration 0 operands)
    uint4 bq0 = *(const uint4*)bp0;
    uint4 bq1 = *(const uint4*)bp1;
    float4 e0 = *(const float4*)&edb[quad * 8];
    float4 e1 = *(const float4*)&edb[quad * 8 + 4];

    f32x4 acc[16][2] = {};
    float lsum0 = 0.f, lsum1 = 0.f;
    int cur = 0;
    for (int it4 = 0; it4 < 8; ++it4) {
        uint4 nbq0, nbq1;
        #pragma unroll
        for (int sub = 0; sub < 4; ++sub) {
            const int it = it4 * 4 + sub;
            pipe_barrier_vm2();
            // register prefetch for it+1, issued BEFORE the DMA so the next barrier's
            // vmcnt(2) drains these (issued a full iteration early) while keeping
            // the newest DMA pair in flight.
            const int itn = (it + 1) & 31;
            float4 ne0 = *(const float4*)&edb[itn * 32 + quad * 8];
            float4 ne1 = *(const float4*)&edb[itn * 32 + quad * 8 + 4];
            if (sub == 0) {
                nbq0 = *(const uint4*)(bp0 + (it4 + 1) * 16);
                nbq1 = *(const uint4*)(bp1 + (it4 + 1) * 16);
            }
            // DMA prefetch iteration it+2
            {
                const int nxt = (cur >= 1) ? cur - 1 : 2;
                const int mbp = ((it + 2) & 31) * 32;
                async_cp16(&Bld[nxt][wv * 512], gb0 + mbp);
                async_cp16(&Bld[nxt][(wv + 8) * 512], gb1 + mbp);
            }
            // P from current registers
            const unsigned d0[4] = {bq0.x, bq0.y, bq0.z, bq0.w};
            const unsigned d1[4] = {bq1.x, bq1.y, bq1.z, bq1.w};
            unsigned bb0 = (d0[sub] >> (quad * 8)) & 0xffu;
            unsigned bb1 = (d1[sub] >> (quad * 8)) & 0xffu;
            float ev[8] = {e0.x, e0.y, e0.z, e0.w, e1.x, e1.y, e1.z, e1.w};
            unsigned up0[8], up1[8];
            #pragma unroll
            for (int j = 0; j < 8; ++j) {
                float s0 = esr0 + ev[j]; s0 = fmaxf(s0, ALPHA * s0);
                float p0 = ((bb0 >> j) & 1u) ? __builtin_amdgcn_exp2f(s0) : 0.f;
                unsigned u0; __builtin_memcpy(&u0, &p0, 4); u0 &= 0xffff0000u;
                float pt0; __builtin_memcpy(&pt0, &u0, 4);
                lsum0 += pt0; up0[j] = u0;
                float s1 = esr1 + ev[j]; s1 = fmaxf(s1, ALPHA * s1);
                float p1 = ((bb1 >> j) & 1u) ? __builtin_amdgcn_exp2f(s1) : 0.f;
                unsigned u1; __builtin_memcpy(&u1, &p1, 4); u1 &= 0xffff0000u;
                float pt1; __builtin_memcpy(&pt1, &u1, 4);
                lsum1 += pt1; up1[j] = u1;
            }
            int pk0[4], pk1[4];
            #pragma unroll
            for (int j = 0; j < 4; ++j) {
                pk0[j] = __builtin_amdgcn_perm(up0[2*j+1], up0[2*j], 0x07060302u);
                pk1[j] = __builtin_amdgcn_perm(up1[2*j+1], up1[2*j], 0x07060302u);
            }
            short8 bfrag0, bfrag1;
            __builtin_memcpy(&bfrag0, pk0, 16);
            __builtin_memcpy(&bfrag1, pk1, 16);
            #pragma unroll
            for (int ot = 0; ot < 16; ++ot) {
                short8 af = *(const short8*)&Bld[cur][ot * 512 + lane * 8];
                acc[ot][0] = __builtin_amdgcn_mfma_f32_16x16x32_bf16(af, bfrag0, acc[ot][0], 0, 0, 0);
                acc[ot][1] = __builtin_amdgcn_mfma_f32_16x16x32_bf16(af, bfrag1, acc[ot][1], 0, 0, 0);
            }
            e0 = ne0; e1 = ne1;
            if (sub == 3) { bq0 = nbq0; bq1 = nbq1; }
            cur = (cur == 2) ? 0 : cur + 1;
        }
    }
    lsum0 += __shfl_xor(lsum0, 16, 64); lsum0 += __shfl_xor(lsum0, 32, 64);
    lsum1 += __shfl_xor(lsum1, 16, 64); lsum1 += __shfl_xor(lsum1, 32, 64);
    if (quad == 0) {
        l1p[(size_t)(kz * NHEAD + h) * N_NODES + m_r0] = lsum0;
        l1p[(size_t)(kz * NHEAD + h) * N_NODES + m_r1] = lsum1;
    }
    unsigned short* Cb = C1p + (size_t)(kz * NHEAD + h) * N_NODES * F_HID;
    #pragma unroll
    for (int ot = 0; ot < 16; ++ot)
      #pragma unroll
      for (int mi = 0; mi < 2; ++mi) {
        int m = (mi == 0) ? m_r0 : m_r1;
        int o0 = ot * 16 + quad * 4;
        uint2 uu;
        uu.x = (unsigned)f2bf(acc[ot][mi][0]) | ((unsigned)f2bf(acc[ot][mi][1]) << 16);
        uu.y = (unsigned)f2bf(acc[ot][mi][2]) | ((unsigned)f2bf(acc[ot][mi][3]) << 16);
        *(uint2*)&Cb[(size_t)m * F_HID + o0] = uu;
      }
}

// ============ K4: combine ksplit+heads, normalize, mean, relu -> h2 bf16 ============
__global__ __launch_bounds__(256) void k_reduce1(const unsigned short* __restrict__ C1p,
                                                 const float* __restrict__ l1p,
                                                 unsigned short* __restrict__ h2) {
    int t = threadIdx.x;
    int og = t & 31, nl = t >> 5;
    int n = blockIdx.x * 8 + nl;
    float acc8[8] = {};
    #pragma unroll
    for (int h = 0; h < NHEAD; ++h) {
        float den = 0.f, num[8] = {};
        #pragma unroll
        for (int kz = 0; kz < 4; ++kz) {
            den += l1p[(size_t)(kz * NHEAD + h) * N_NODES + n];
            uint4 u = *(const uint4*)&C1p[((size_t)(kz * NHEAD + h) * N_NODES + n) * F_HID + og * 8];
            num[0] += lo_bf(u.x); num[1] += hi_bf(u.x);
            num[2] += lo_bf(u.y); num[3] += hi_bf(u.y);
            num[4] += lo_bf(u.z); num[5] += hi_bf(u.z);
            num[6] += lo_bf(u.w); num[7] += hi_bf(u.w);
        }
        float rinv = 1.f / fmaxf(den, 1e-30f);
        #pragma unroll
        for (int j = 0; j < 8; ++j) acc8[j] += num[j] * rinv;
    }
    uint4 w;
    unsigned short bq[8];
    #pragma unroll
    for (int j = 0; j < 8; ++j) bq[j] = f2bf(fmaxf(acc8[j] * 0.25f, 0.f));
    w.x = (unsigned)bq[0] | ((unsigned)bq[1] << 16);
    w.y = (unsigned)bq[2] | ((unsigned)bq[3] << 16);
    w.z = (unsigned)bq[4] | ((unsigned)bq[5] << 16);
    w.w = (unsigned)bq[6] | ((unsigned)bq[7] << 16);
    *(uint4*)&h2[(size_t)n * F_HID + og * 8] = w;
}

// ============ K5: h2wt[c][n] = h2[n]·W2t[c], e_src2/e_dst2 (scaled by log2e) ============
__global__ __launch_bounds__(256) void k_h2w(const unsigned short* __restrict__ h2,
                                             const float* __restrict__ W2t,
                                             const float* __restrict__ a2,
                                             unsigned short* __restrict__ h2wt,
                                             float* __restrict__ es2, float* __restrict__ ed2) {
    int t = threadIdx.x;
    int c = t & 15, nl = t >> 4;
    int n = blockIdx.x * 16 + nl;
    const unsigned short* hrow = h2 + (size_t)n * F_HID;
    const float* wrow = W2t + c * F_HID;
    float dot = 0.f;
    for (int o = 0; o < F_HID; o += 8) {
        uint4 hu = *(const uint4*)&hrow[o];
        float4 w0 = *(const float4*)&wrow[o];
        float4 w1 = *(const float4*)&wrow[o + 4];
        dot += lo_bf(hu.x)*w0.x + hi_bf(hu.x)*w0.y + lo_bf(hu.y)*w0.z + hi_bf(hu.y)*w0.w;
        dot += lo_bf(hu.z)*w1.x + hi_bf(hu.z)*w1.y + lo_bf(hu.w)*w1.z + hi_bf(hu.w)*w1.w;
    }
    h2wt[(size_t)c * N_NODES + n] = f2bf(dot);
    float es = dot * a2[c] * LOG2E;
    float ed = dot * a2[F_CLS + c] * LOG2E;
    #pragma unroll
    for (int off = 1; off < 16; off <<= 1) {
        es += __shfl_xor(es, off, 64);
        ed += __shfl_xor(ed, off, 64);
    }
    if (c == 0) { es2[n] = es; ed2[n] = ed; }
}

// ============ K6: layer-2 fused softmax-GEMM — reg-pipelined, no LDS/barriers, ksplit=8 ============
__global__ __launch_bounds__(256, 4) void k_attn2(const unsigned short* __restrict__ h2wt,
                                                  const float* __restrict__ es2,
                                                  const float* __restrict__ ed2,
                                                  const unsigned char* __restrict__ bmb,
                                                  float* __restrict__ out2p,
                                                  float* __restrict__ l2p) {
    const int t = threadIdx.x;
    const int lane = t & 63, wv = t >> 6, quad = lane >> 4, l15 = lane & 15;
    const int m0 = blockIdx.x * 64;
    const int ks = blockIdx.y;
    const int mb0 = ks * 512;
    const int m_r = m0 + wv * 16 + l15;
    const float esr = es2[m_r];
    const unsigned char* bp = bmb + (size_t)m_r * (N_NODES / 8) + (mb0 >> 3);
    const float* edb = ed2 + mb0;
    const unsigned short* hb = h2wt + (size_t)l15 * N_NODES + mb0 + quad * 8;

    uint4 bq = *(const uint4*)bp;
    float4 e0 = *(const float4*)&edb[quad * 8];
    float4 e1 = *(const float4*)&edb[quad * 8 + 4];
    short8 bfr = *(const short8*)&hb[0];

    f32x4 acc = {};
    float lsum = 0.f;
    for (int it4 = 0; it4 < 4; ++it4) {
        uint4 nbq;
        #pragma unroll
        for (int sub = 0; sub < 4; ++sub) {
            const int it = it4 * 4 + sub;
            const int itn = (it + 1) & 15;
            float4 ne0 = *(const float4*)&edb[itn * 32 + quad * 8];
            float4 ne1 = *(const float4*)&edb[itn * 32 + quad * 8 + 4];
            short8 nbf = *(const short8*)&hb[itn * 32];
            if (sub == 0) nbq = *(const uint4*)(bp + (it4 + 1) * 16);
            const unsigned d[4] = {bq.x, bq.y, bq.z, bq.w};
            unsigned bb = (d[sub] >> (quad * 8)) & 0xffu;
            float ev[8] = {e0.x, e0.y, e0.z, e0.w, e1.x, e1.y, e1.z, e1.w};
            short8 afrag;
            #pragma unroll
            for (int j = 0; j < 8; ++j) {
                float s = esr + ev[j]; s = fmaxf(s, ALPHA * s);
                float p = ((bb >> j) & 1u) ? __builtin_amdgcn_exp2f(s) : 0.f;
                lsum += p; afrag[j] = (short)f2bf(p);
            }
            acc = __builtin_amdgcn_mfma_f32_16x16x32_bf16(afrag, bfr, acc, 0, 0, 0);
            e0 = ne0; e1 = ne1; bfr = nbf;
            if (sub == 3) bq = nbq;
        }
    }
    lsum += __shfl_xor(lsum, 16, 64); lsum += __shfl_xor(lsum, 32, 64);
    if (quad == 0) l2p[(size_t)ks * N_NODES + m_r] = lsum;
    #pragma unroll
    for (int rg = 0; rg < 4; ++rg) {
        int row = m0 + wv * 16 + quad * 4 + rg;
        out2p[((size_t)ks * N_NODES + row) * F_CLS + l15] = acc[rg];
    }
}

// ============ K7: combine ksplit, normalize, log_softmax -> fp32 ============
__global__ __launch_bounds__(256) void k_final(const float* __restrict__ out2p,
                                               const float* __restrict__ l2p,
                                               float* __restrict__ out) {
    int t = threadIdx.x;
    int c = t & 15, nl = t >> 4;
    int n = blockIdx.x * 16 + nl;
    float v = 0.f, l = 0.f;
    #pragma unroll
    for (int ks = 0; ks < 8; ++ks) {
        v += out2p[((size_t)ks * N_NODES + n) * F_CLS + c];
        l += l2p[(size_t)ks * N_NODES + n];
    }
    v /= fmaxf(l, 1e-30f);
    float mx = v;
    #pragma unroll
    for (int off = 1; off < 16; off <<= 1) mx = fmaxf(mx, __shfl_xor(mx, off, 64));
    float e = __expf(v - mx);
    float se = e;
    #pragma unroll
    for (int off = 1; off < 16; off <<= 1) se += __shfl_xor(se, off, 64);
    out[(size_t)n * F_CLS + c] = v - mx - __logf(se);
}

// ---------------- workspace layout (bytes) ----------------
#define OFF_BM    0ull                      // 2 MB   bitmask
#define OFF_XB    2097152ull                // 4 MB   x bf16
#define OFF_W1T   6291456ull                // 1 MB   W1t bf16
#define OFF_W2T   7340032ull                // 16 KB  W2t fp32
#define OFF_ES1   7356416ull                // 64 KB  (zeroed with ED1 in k_prep)
#define OFF_ED1   7421952ull                // 64 KB
#define OFF_ES2   7487488ull                // 16 KB
#define OFF_ED2   7503872ull                // 16 KB
#define OFF_L1P   7520256ull                // 256 KB [kz][h][n]
#define OFF_L2P   7782400ull                // 128 KB [ks][n]
#define OFF_H2    7910400ull                // 2 MB   bf16 (dead after k_h2w)
#define OFF_OUT2P 7910400ull                // 2 MB   fp32 — aliases H2
#define OFF_H2WT  10007552ull               // 128 KB bf16
#define OFF_H1T   10138624ull               // 8 MB   [h][o][n] bf16
#define OFF_C1P   18527232ull               // 16 MB  bf16 [kz][h][m][o]

extern "C" void kernel_launch(void* const* d_in, const int* in_sizes, int n_in,
                              void* d_out, int out_size, void* d_ws, size_t ws_size,
                              hipStream_t stream) {
    const float* x   = (const float*)d_in[0];
    const int*   adj = (const int*)d_in[1];
    const float* W1  = (const float*)d_in[2];
    const float* a1  = (const float*)d_in[3];
    const float* W2  = (const float*)d_in[4];
    const float* a2  = (const float*)d_in[5];
    float* out = (float*)d_out;
    char* ws = (char*)d_ws;

    unsigned long long* bm  = (unsigned long long*)(ws + OFF_BM);
    unsigned char*      bmb = (unsigned char*)(ws + OFF_BM);
    unsigned short* xb   = (unsigned short*)(ws + OFF_XB);
    unsigned short* W1t  = (unsigned short*)(ws + OFF_W1T);
    float* W2t   = (float*)(ws + OFF_W2T);
    float* es1   = (float*)(ws + OFF_ES1);
    float* ed1   = (float*)(ws + OFF_ED1);
    float* es2   = (float*)(ws + OFF_ES2);
    float* ed2   = (float*)(ws + OFF_ED2);
    float* l1p   = (float*)(ws + OFF_L1P);
    float* l2p   = (float*)(ws + OFF_L2P);
    unsigned short* h2   = (unsigned short*)(ws + OFF_H2);
    float* out2p = (float*)(ws + OFF_OUT2P);
    unsigned short* h2wt = (unsigned short*)(ws + OFF_H2WT);
    unsigned short* h1t  = (unsigned short*)(ws + OFF_H1T);
    unsigned short* C1p  = (unsigned short*)(ws + OFF_C1P);

    k_prep    <<<dim3(PREP_BM_BLOCKS + PREP_CV_BLOCKS + PREP_Z_BLOCKS), 256, 0, stream>>>(
                  adj, x, W1, W2, bm, xb, W1t, W2t, es1);
    k_gemm1   <<<dim3(32, 4, 4), 256, 0, stream>>>(xb, W1t, a1, h1t, es1, ed1);
    k_attn1   <<<dim3(16, 4, 4), 512, 0, stream>>>(h1t, es1, ed1, bmb, C1p, l1p);
    k_reduce1 <<<dim3(512),      256, 0, stream>>>(C1p, l1p, h2);
    k_h2w     <<<dim3(256),      256, 0, stream>>>(h2, W2t, a2, h2wt, es2, ed2);
    k_attn2   <<<dim3(64, 8),    256, 0, stream>>>(h2wt, es2, ed2, bmb, out2p, l2p);
    k_final   <<<dim3(256),      256, 0, stream>>>(out2p, l2p, out);
}

// Round 8
// 396.835 us; speedup vs baseline: 1.5048x; 1.1639x over previous
//
#include <hip/hip_runtime.h>
#include <stdint.h>

#define N_NODES 4096
#define F_IN    512
#define F_HID   256
#define F_CLS   16
#define NHEAD   4
#define ALPHA   0.2f
#define LOG2E   1.4426950408889634f

typedef __attribute__((ext_vector_type(8))) short short8;
typedef __attribute__((ext_vector_type(4))) float f32x4;

__device__ __forceinline__ float bf2f(unsigned short h) {
    unsigned u = ((unsigned)h) << 16; float f; __builtin_memcpy(&f, &u, 4); return f;
}
__device__ __forceinline__ unsigned short f2bf(float f) {
    unsigned u; __builtin_memcpy(&u, &f, 4);
    u += 0x7fffu + ((u >> 16) & 1u);
    return (unsigned short)(u >> 16);
}
__device__ __forceinline__ float lo_bf(unsigned u) { u <<= 16;          float f; __builtin_memcpy(&f,&u,4); return f; }
__device__ __forceinline__ float hi_bf(unsigned u) { u &= 0xffff0000u;  float f; __builtin_memcpy(&f,&u,4); return f; }

__device__ __forceinline__ void async_cp16(void* lds, const void* g) {
    __builtin_amdgcn_global_load_lds(
        (const __attribute__((address_space(1))) unsigned int*)g,
        (__attribute__((address_space(3))) unsigned int*)lds,
        16, 0, 0);
}

// s_waitcnt imm: vmcnt[3:0], expcnt[6:4]=7 (nowait), lgkmcnt[11:8]
__device__ __forceinline__ void pipe_barrier_vm2() {
    __builtin_amdgcn_sched_barrier(0);
    __builtin_amdgcn_s_waitcnt(0x0072);   // vmcnt(2) lgkmcnt(0)
    __builtin_amdgcn_s_barrier();
    __builtin_amdgcn_sched_barrier(0);
}
__device__ __forceinline__ void pipe_barrier_vm3() {
    __builtin_amdgcn_sched_barrier(0);
    __builtin_amdgcn_s_waitcnt(0x0073);   // vmcnt(3) lgkmcnt(0)
    __builtin_amdgcn_s_barrier();
    __builtin_amdgcn_sched_barrier(0);
}

// ============ K1: fused prep: adj->bitmask | fp32->bf16 converts | zero es1/ed1 ============
#define PREP_BM_BLOCKS   16384
#define PREP_CV_BLOCKS   1296
#define PREP_Z_BLOCKS    4
__global__ __launch_bounds__(256) void k_prep(const int* __restrict__ adj,
                                              const float* __restrict__ x,
                                              const float* __restrict__ W1,
                                              const float* __restrict__ W2,
                                              unsigned long long* __restrict__ bm,
                                              unsigned short* __restrict__ xb,
                                              unsigned short* __restrict__ W1t,
                                              float* __restrict__ W2t,
                                              float* __restrict__ ez) {
    int b = blockIdx.x;
    if (b < PREP_BM_BLOCKS) {
        int wv = threadIdx.x >> 6, lane = threadIdx.x & 63;
        int idx0 = b * 1024 + wv * 256;
        const int* p = adj + idx0 + lane;
        unsigned long long m0 = __ballot(p[0]   > 0);
        unsigned long long m1 = __ballot(p[64]  > 0);
        unsigned long long m2 = __ballot(p[128] > 0);
        unsigned long long m3 = __ballot(p[192] > 0);
        if (lane == 0) {
            int w = idx0 >> 6;
            bm[w] = m0; bm[w+1] = m1; bm[w+2] = m2; bm[w+3] = m3;
        }
        return;
    }
    if (b < PREP_BM_BLOCKS + PREP_CV_BLOCKS) {
        int tid = (b - PREP_BM_BLOCKS) * 256 + threadIdx.x;
        const int NXV = (N_NODES * F_IN) / 8;       // 262144
        const int NW1 = NHEAD * 64 * F_HID;         // 65536
        if (tid < NXV) {
            float4 a = *(const float4*)&x[tid * 8];
            float4 c = *(const float4*)&x[tid * 8 + 4];
            uint4 w;
            w.x = (unsigned)f2bf(a.x) | ((unsigned)f2bf(a.y) << 16);
            w.y = (unsigned)f2bf(a.z) | ((unsigned)f2bf(a.w) << 16);
            w.z = (unsigned)f2bf(c.x) | ((unsigned)f2bf(c.y) << 16);
            w.w = (unsigned)f2bf(c.z) | ((unsigned)f2bf(c.w) << 16);
            *(uint4*)&xb[tid * 8] = w;
        } else if (tid < NXV + NW1) {
            int j = tid - NXV;
            int o = j & 255, f8 = (j >> 8) & 63, h = j >> 14;
            float v[8];
            #pragma unroll
            for (int k = 0; k < 8; ++k)
                v[k] = W1[(size_t)(h * F_IN + f8 * 8 + k) * F_HID + o];
            uint4 w;
            w.x = (unsigned)f2bf(v[0]) | ((unsigned)f2bf(v[1]) << 16);
            w.y = (unsigned)f2bf(v[2]) | ((unsigned)f2bf(v[3]) << 16);
            w.z = (unsigned)f2bf(v[4]) | ((unsigned)f2bf(v[5]) << 16);
            w.w = (unsigned)f2bf(v[6]) | ((unsigned)f2bf(v[7]) << 16);
            *(uint4*)&W1t[(size_t)(h * F_HID + o) * F_IN + f8 * 8] = w;
        } else {
            int j = tid - NXV - NW1;
            if (j < F_HID * F_CLS) {
                int o = j >> 4, c = j & 15;
                W2t[c * F_HID + o] = W2[j];
            }
        }
        return;
    }
    {
        int zb = b - PREP_BM_BLOCKS - PREP_CV_BLOCKS;
        float4* z4 = (float4*)ez;
        #pragma unroll
        for (int r = 0; r < 8; ++r)
            z4[zb * 2048 + r * 256 + threadIdx.x] = make_float4(0.f, 0.f, 0.f, 0.f);
    }
}

// ============ K2: h1t[h][o][n] GEMM + fused e1 — triple-buffer pipeline ============
__global__ __launch_bounds__(256, 4) void k_gemm1(const unsigned short* __restrict__ xb,
                                                  const unsigned short* __restrict__ W1t,
                                                  const float* __restrict__ a1,
                                                  unsigned short* __restrict__ h1t,
                                                  float* __restrict__ es1,
                                                  float* __restrict__ ed1) {
    __shared__ unsigned short Sld[3][6144];
    const int t = threadIdx.x;
    const int lane = t & 63, wv = t >> 6, quad = lane >> 4, l15 = lane & 15;
    const int wn = wv & 1, wo = wv >> 1;
    const int n0 = blockIdx.x * 128;
    const int oo0 = blockIdx.y * 64;
    const int h = blockIdx.z;
    const int kl = (lane >> 4) * 8;

    const unsigned short* gs[3];
    int loff[3];
    #pragma unroll
    for (int s = 0; s < 3; ++s) {
        int c = wv * 3 + s;
        loff[s] = c * 512;
        gs[s] = (c < 8)
            ? (xb  + (size_t)(n0 + c * 16 + l15) * F_IN + kl)
            : (W1t + (size_t)(h * F_HID + oo0 + (c - 8) * 16 + l15) * F_IN + kl);
    }
    #pragma unroll
    for (int s = 0; s < 3; ++s) async_cp16(&Sld[0][loff[s]], gs[s]);
    #pragma unroll
    for (int s = 0; s < 3; ++s) async_cp16(&Sld[1][loff[s]], gs[s] + 32);

    f32x4 acc[4][2] = {};
    int cur = 0;
    for (int it = 0; it < 16; ++it) {
        pipe_barrier_vm3();
        {
            const int nxt = (cur >= 1) ? cur - 1 : 2;
            const int off = ((it + 2) & 15) * 32;
            #pragma unroll
            for (int s = 0; s < 3; ++s) async_cp16(&Sld[nxt][loff[s]], gs[s] + off);
        }
        short8 bfw[2];
        #pragma unroll
        for (int mi = 0; mi < 2; ++mi)
            bfw[mi] = *(const short8*)&Sld[cur][(8 + wo * 2 + mi) * 512 + lane * 8];
        #pragma unroll
        for (int ni = 0; ni < 4; ++ni) {
            short8 af = *(const short8*)&Sld[cur][(wn * 4 + ni) * 512 + lane * 8];
            #pragma unroll
            for (int mi = 0; mi < 2; ++mi)
                acc[ni][mi] = __builtin_amdgcn_mfma_f32_16x16x32_bf16(af, bfw[mi], acc[ni][mi], 0, 0, 0);
        }
        cur = (cur == 2) ? 0 : cur + 1;
    }
    #pragma unroll
    for (int ni = 0; ni < 4; ++ni)
      #pragma unroll
      for (int mi = 0; mi < 2; ++mi) {
        int o = oo0 + wo * 32 + mi * 16 + l15;
        int nb = n0 + wn * 64 + ni * 16 + quad * 4;
        uint2 uu;
        uu.x = (unsigned)f2bf(acc[ni][mi][0]) | ((unsigned)f2bf(acc[ni][mi][1]) << 16);
        uu.y = (unsigned)f2bf(acc[ni][mi][2]) | ((unsigned)f2bf(acc[ni][mi][3]) << 16);
        *(uint2*)&h1t[(size_t)(h * F_HID + o) * N_NODES + nb] = uu;
      }
    float a1s[2], a1d[2];
    #pragma unroll
    for (int mi = 0; mi < 2; ++mi) {
        int o = oo0 + wo * 32 + mi * 16 + l15;
        a1s[mi] = a1[h * 2 * F_HID + o] * LOG2E;
        a1d[mi] = a1[h * 2 * F_HID + F_HID + o] * LOG2E;
    }
    #pragma unroll
    for (int ni = 0; ni < 4; ++ni) {
        #pragma unroll
        for (int rg = 0; rg < 4; ++rg) {
            float es = acc[ni][0][rg] * a1s[0] + acc[ni][1][rg] * a1s[1];
            float ed = acc[ni][0][rg] * a1d[0] + acc[ni][1][rg] * a1d[1];
            #pragma unroll
            for (int off = 1; off < 16; off <<= 1) {
                es += __shfl_xor(es, off, 64);
                ed += __shfl_xor(ed, off, 64);
            }
            if (l15 == 0) {
                int n = n0 + wn * 64 + ni * 16 + quad * 4 + rg;
                atomicAdd(&es1[h * N_NODES + n], es);
                atomicAdd(&ed1[h * N_NODES + n], ed);
            }
        }
    }
}

// ============ K3: fused masked-softmax-GEMM layer 1 ============
// Round-5 config (BM=256, 8 waves x 32 m, o=256/wave, grid (16,4,4), triple-buffer
// vm2) + ONLY delta: bitmask via uint4 per 4 iters (no scattered ubyte loads).
// Register budget: acc 128 AGPR + ~116 VGPR < 256/wave (launch_bounds 512,2) — no spill.
__global__ __launch_bounds__(512, 2) void k_attn1(const unsigned short* __restrict__ h1t,
                                                  const float* __restrict__ es1,
                                                  const float* __restrict__ ed1,
                                                  const unsigned char* __restrict__ bmb,
                                                  unsigned short* __restrict__ C1p,
                                                  float* __restrict__ l1p) {
    __shared__ unsigned short Bld[3][8192];   // 3 x 16 KB, frag order
    const int t = threadIdx.x;
    const int lane = t & 63, wv = t >> 6, quad = lane >> 4, l15 = lane & 15;
    const int m0 = blockIdx.x * 256;
    const int h = blockIdx.y;
    const int kz = blockIdx.z;
    const int mb0 = kz * 1024;

    const int m_r0 = m0 + wv * 32 + l15;
    const int m_r1 = m_r0 + 16;
    const float esr0 = es1[h * N_NODES + m_r0];   // pre-scaled by log2e
    const float esr1 = es1[h * N_NODES + m_r1];
    const unsigned char* bp0 = bmb + (size_t)m_r0 * (N_NODES / 8) + (mb0 >> 3);
    const unsigned char* bp1 = bmb + (size_t)m_r1 * (N_NODES / 8) + (mb0 >> 3);
    const float* edb = ed1 + h * N_NODES + mb0;

    const unsigned short* gb0 = h1t + (size_t)(h * F_HID + wv * 16 + l15) * N_NODES + mb0 + quad * 8;
    const unsigned short* gb1 = h1t + (size_t)(h * F_HID + (wv + 8) * 16 + l15) * N_NODES + mb0 + quad * 8;
    async_cp16(&Bld[0][wv * 512], gb0);
    async_cp16(&Bld[0][(wv + 8) * 512], gb1);
    async_cp16(&Bld[1][wv * 512], gb0 + 32);
    async_cp16(&Bld[1][(wv + 8) * 512], gb1 + 32);

    uint4 bq0 = *(const uint4*)bp0;
    uint4 bq1 = *(const uint4*)bp1;

    f32x4 acc[16][2] = {};
    float lsum0 = 0.f, lsum1 = 0.f;
    int cur = 0;
    for (int it4 = 0; it4 < 8; ++it4) {
        uint4 nbq0, nbq1;
        #pragma unroll
        for (int sub = 0; sub < 4; ++sub) {
            const int it = it4 * 4 + sub;
            const int mb = it * 32;
            pipe_barrier_vm2();
            if (sub == 0) {   // next group's bitmask, 4 iters ahead (wrapped tail, dead)
                nbq0 = *(const uint4*)(bp0 + ((it4 + 1) & 7) * 16);
                nbq1 = *(const uint4*)(bp1 + ((it4 + 1) & 7) * 16);
            }
            // DMA prefetch iteration it+2
            {
                const int nxt = (cur >= 1) ? cur - 1 : 2;
                const int mbp = ((it + 2) & 31) * 32;
                async_cp16(&Bld[nxt][wv * 512], gb0 + mbp);
                async_cp16(&Bld[nxt][(wv + 8) * 512], gb1 + mbp);
            }
            float4 e0 = *(const float4*)&edb[mb + quad * 8];
            float4 e1v = *(const float4*)&edb[mb + quad * 8 + 4];
            float ev[8] = {e0.x, e0.y, e0.z, e0.w, e1v.x, e1v.y, e1v.z, e1v.w};
            const unsigned d0[4] = {bq0.x, bq0.y, bq0.z, bq0.w};
            const unsigned d1[4] = {bq1.x, bq1.y, bq1.z, bq1.w};
            unsigned bb0 = (d0[sub] >> (quad * 8)) & 0xffu;
            unsigned bb1 = (d1[sub] >> (quad * 8)) & 0xffu;
            unsigned up0[8], up1[8];
            #pragma unroll
            for (int j = 0; j < 8; ++j) {
                float s0 = esr0 + ev[j]; s0 = fmaxf(s0, ALPHA * s0);
                float p0 = ((bb0 >> j) & 1u) ? __builtin_amdgcn_exp2f(s0) : 0.f;
                unsigned u0; __builtin_memcpy(&u0, &p0, 4); u0 &= 0xffff0000u;
                float pt0; __builtin_memcpy(&pt0, &u0, 4);
                lsum0 += pt0; up0[j] = u0;
                float s1 = esr1 + ev[j]; s1 = fmaxf(s1, ALPHA * s1);
                float p1 = ((bb1 >> j) & 1u) ? __builtin_amdgcn_exp2f(s1) : 0.f;
                unsigned u1; __builtin_memcpy(&u1, &p1, 4); u1 &= 0xffff0000u;
                float pt1; __builtin_memcpy(&pt1, &u1, 4);
                lsum1 += pt1; up1[j] = u1;
            }
            int pk0[4], pk1[4];
            #pragma unroll
            for (int j = 0; j < 4; ++j) {
                pk0[j] = __builtin_amdgcn_perm(up0[2*j+1], up0[2*j], 0x07060302u);
                pk1[j] = __builtin_amdgcn_perm(up1[2*j+1], up1[2*j], 0x07060302u);
            }
            short8 bfrag0, bfrag1;
            __builtin_memcpy(&bfrag0, pk0, 16);
            __builtin_memcpy(&bfrag1, pk1, 16);
            #pragma unroll
            for (int ot = 0; ot < 16; ++ot) {
                short8 af = *(const short8*)&Bld[cur][ot * 512 + lane * 8];
                acc[ot][0] = __builtin_amdgcn_mfma_f32_16x16x32_bf16(af, bfrag0, acc[ot][0], 0, 0, 0);
                acc[ot][1] = __builtin_amdgcn_mfma_f32_16x16x32_bf16(af, bfrag1, acc[ot][1], 0, 0, 0);
            }
            if (sub == 3) { bq0 = nbq0; bq1 = nbq1; }
            cur = (cur == 2) ? 0 : cur + 1;
        }
    }
    lsum0 += __shfl_xor(lsum0, 16, 64); lsum0 += __shfl_xor(lsum0, 32, 64);
    lsum1 += __shfl_xor(lsum1, 16, 64); lsum1 += __shfl_xor(lsum1, 32, 64);
    if (quad == 0) {
        l1p[(size_t)(kz * NHEAD + h) * N_NODES + m_r0] = lsum0;
        l1p[(size_t)(kz * NHEAD + h) * N_NODES + m_r1] = lsum1;
    }
    unsigned short* Cb = C1p + (size_t)(kz * NHEAD + h) * N_NODES * F_HID;
    #pragma unroll
    for (int ot = 0; ot < 16; ++ot)
      #pragma unroll
      for (int mi = 0; mi < 2; ++mi) {
        int m = (mi == 0) ? m_r0 : m_r1;
        int o0 = ot * 16 + quad * 4;
        uint2 uu;
        uu.x = (unsigned)f2bf(acc[ot][mi][0]) | ((unsigned)f2bf(acc[ot][mi][1]) << 16);
        uu.y = (unsigned)f2bf(acc[ot][mi][2]) | ((unsigned)f2bf(acc[ot][mi][3]) << 16);
        *(uint2*)&Cb[(size_t)m * F_HID + o0] = uu;
      }
}

// ============ K4: FUSED reduce1 + h2w: C1p -> h2 (LDS only) -> h2wt, es2, ed2 ============
// grid 512 blocks x 256 thr; 8 nodes/block. h2 never touches global.
__global__ __launch_bounds__(256) void k_reduce_h2w(const unsigned short* __restrict__ C1p,
                                                    const float* __restrict__ l1p,
                                                    const float* __restrict__ W2t,
                                                    const float* __restrict__ a2,
                                                    unsigned short* __restrict__ h2wt,
                                                    float* __restrict__ es2,
                                                    float* __restrict__ ed2) {
    __shared__ float h2s[8][256];
    int t = threadIdx.x;
    int og = t & 31, nl = t >> 5;             // 32 threads per node, 8 o each
    int n = blockIdx.x * 8 + nl;
    float acc8[8] = {};
    #pragma unroll
    for (int h = 0; h < NHEAD; ++h) {
        float den = 0.f, num[8] = {};
        #pragma unroll
        for (int kz = 0; kz < 4; ++kz) {
            den += l1p[(size_t)(kz * NHEAD + h) * N_NODES + n];
            uint4 u = *(const uint4*)&C1p[((size_t)(kz * NHEAD + h) * N_NODES + n) * F_HID + og * 8];
            num[0] += lo_bf(u.x); num[1] += hi_bf(u.x);
            num[2] += lo_bf(u.y); num[3] += hi_bf(u.y);
            num[4] += lo_bf(u.z); num[5] += hi_bf(u.z);
            num[6] += lo_bf(u.w); num[7] += hi_bf(u.w);
        }
        float rinv = 1.f / fmaxf(den, 1e-30f);
        #pragma unroll
        for (int j = 0; j < 8; ++j) acc8[j] += num[j] * rinv;
    }
    #pragma unroll
    for (int j = 0; j < 8; ++j) {
        float v = fmaxf(acc8[j] * 0.25f, 0.f);
        h2s[nl][og * 8 + j] = bf2f(f2bf(v));   // keep bf16-rounded value (matches prior math)
    }
    __syncthreads();
    if (t < 128) {
        int c = t & 15, n2l = t >> 4;
        int n2 = blockIdx.x * 8 + n2l;
        const float* wrow = W2t + c * F_HID;
        const float* hrow = h2s[n2l];
        float dot = 0.f;
        #pragma unroll 4
        for (int o = 0; o < F_HID; o += 8) {
            float4 hv0 = *(const float4*)&hrow[o];
            float4 hv1 = *(const float4*)&hrow[o + 4];
            float4 w0 = *(const float4*)&wrow[o];
            float4 w1 = *(const float4*)&wrow[o + 4];
            dot += hv0.x*w0.x + hv0.y*w0.y + hv0.z*w0.z + hv0.w*w0.w;
            dot += hv1.x*w1.x + hv1.y*w1.y + hv1.z*w1.z + hv1.w*w1.w;
        }
        h2wt[(size_t)c * N_NODES + n2] = f2bf(dot);
        float es = dot * a2[c] * LOG2E;
        float ed = dot * a2[F_CLS + c] * LOG2E;
        #pragma unroll
        for (int off = 1; off < 16; off <<= 1) {
            es += __shfl_xor(es, off, 64);
            ed += __shfl_xor(ed, off, 64);
        }
        if (c == 0) { es2[n2] = es; ed2[n2] = ed; }
    }
}

// ============ K5: layer-2 fused softmax-GEMM — simple (round-5), ksplit=8 ============
__global__ __launch_bounds__(256, 4) void k_attn2(const unsigned short* __restrict__ h2wt,
                                                  const float* __restrict__ es2,
                                                  const float* __restrict__ ed2,
                                                  const unsigned char* __restrict__ bmb,
                                                  float* __restrict__ out2p,
                                                  float* __restrict__ l2p) {
    const int t = threadIdx.x;
    const int lane = t & 63, wv = t >> 6, quad = lane >> 4, l15 = lane & 15;
    const int m0 = blockIdx.x * 64;
    const int ks = blockIdx.y;
    const int m_r = m0 + wv * 16 + l15;
    const float esr = es2[m_r];
    const unsigned char* bp = bmb + (size_t)m_r * (N_NODES / 8);

    f32x4 acc = {};
    float lsum = 0.f;
    for (int it = 0; it < 16; ++it) {
        const int mb = ks * 512 + it * 32;
        float4 e0 = *(const float4*)&ed2[mb + quad * 8];
        float4 e1v = *(const float4*)&ed2[mb + quad * 8 + 4];
        float ev[8] = {e0.x, e0.y, e0.z, e0.w, e1v.x, e1v.y, e1v.z, e1v.w};
        unsigned bb = bp[(mb >> 3) + quad];
        short8 afrag;
        #pragma unroll
        for (int j = 0; j < 8; ++j) {
            float s = esr + ev[j]; s = fmaxf(s, ALPHA * s);
            float p = ((bb >> j) & 1u) ? __builtin_amdgcn_exp2f(s) : 0.f;
            lsum += p; afrag[j] = (short)f2bf(p);
        }
        short8 bfr = *(const short8*)&h2wt[(size_t)l15 * N_NODES + mb + quad * 8];
        acc = __builtin_amdgcn_mfma_f32_16x16x32_bf16(afrag, bfr, acc, 0, 0, 0);
    }
    lsum += __shfl_xor(lsum, 16, 64); lsum += __shfl_xor(lsum, 32, 64);
    if (quad == 0) l2p[(size_t)ks * N_NODES + m_r] = lsum;
    #pragma unroll
    for (int rg = 0; rg < 4; ++rg) {
        int row = m0 + wv * 16 + quad * 4 + rg;
        out2p[((size_t)ks * N_NODES + row) * F_CLS + l15] = acc[rg];
    }
}

// ============ K6: combine ksplit, normalize, log_softmax -> fp32 ============
__global__ __launch_bounds__(256) void k_final(const float* __restrict__ out2p,
                                               const float* __restrict__ l2p,
                                               float* __restrict__ out) {
    int t = threadIdx.x;
    int c = t & 15, nl = t >> 4;
    int n = blockIdx.x * 16 + nl;
    float v = 0.f, l = 0.f;
    #pragma unroll
    for (int ks = 0; ks < 8; ++ks) {
        v += out2p[((size_t)ks * N_NODES + n) * F_CLS + c];
        l += l2p[(size_t)ks * N_NODES + n];
    }
    v /= fmaxf(l, 1e-30f);
    float mx = v;
    #pragma unroll
    for (int off = 1; off < 16; off <<= 1) mx = fmaxf(mx, __shfl_xor(mx, off, 64));
    float e = __expf(v - mx);
    float se = e;
    #pragma unroll
    for (int off = 1; off < 16; off <<= 1) se += __shfl_xor(se, off, 64);
    out[(size_t)n * F_CLS + c] = v - mx - __logf(se);
}

// ---------------- workspace layout (bytes) ----------------
#define OFF_BM    0ull                      // 2 MB   bitmask
#define OFF_XB    2097152ull                // 4 MB   x bf16
#define OFF_W1T   6291456ull                // 1 MB   W1t bf16
#define OFF_W2T   7340032ull                // 16 KB  W2t fp32
#define OFF_ES1   7356416ull                // 64 KB  (zeroed with ED1 in k_prep)
#define OFF_ED1   7421952ull                // 64 KB
#define OFF_ES2   7487488ull                // 16 KB
#define OFF_ED2   7503872ull                // 16 KB
#define OFF_L1P   7520256ull                // 256 KB [kz][h][n]
#define OFF_L2P   7782400ull                // 128 KB [ks][n]
#define OFF_OUT2P 7910400ull                // 2 MB   fp32 [ks][n][c]
#define OFF_H2WT  10007552ull               // 128 KB bf16
#define OFF_H1T   10138624ull               // 8 MB   [h][o][n] bf16
#define OFF_C1P   18527232ull               // 16 MB  bf16 [kz][h][m][o]

extern "C" void kernel_launch(void* const* d_in, const int* in_sizes, int n_in,
                              void* d_out, int out_size, void* d_ws, size_t ws_size,
                              hipStream_t stream) {
    const float* x   = (const float*)d_in[0];
    const int*   adj = (const int*)d_in[1];
    const float* W1  = (const float*)d_in[2];
    const float* a1  = (const float*)d_in[3];
    const float* W2  = (const float*)d_in[4];
    const float* a2  = (const float*)d_in[5];
    float* out = (float*)d_out;
    char* ws = (char*)d_ws;

    unsigned long long* bm  = (unsigned long long*)(ws + OFF_BM);
    unsigned char*      bmb = (unsigned char*)(ws + OFF_BM);
    unsigned short* xb   = (unsigned short*)(ws + OFF_XB);
    unsigned short* W1t  = (unsigned short*)(ws + OFF_W1T);
    float* W2t   = (float*)(ws + OFF_W2T);
    float* es1   = (float*)(ws + OFF_ES1);
    float* ed1   = (float*)(ws + OFF_ED1);
    float* es2   = (float*)(ws + OFF_ES2);
    float* ed2   = (float*)(ws + OFF_ED2);
    float* l1p   = (float*)(ws + OFF_L1P);
    float* l2p   = (float*)(ws + OFF_L2P);
    float* out2p = (float*)(ws + OFF_OUT2P);
    unsigned short* h2wt = (unsigned short*)(ws + OFF_H2WT);
    unsigned short* h1t  = (unsigned short*)(ws + OFF_H1T);
    unsigned short* C1p  = (unsigned short*)(ws + OFF_C1P);

    k_prep       <<<dim3(PREP_BM_BLOCKS + PREP_CV_BLOCKS + PREP_Z_BLOCKS), 256, 0, stream>>>(
                     adj, x, W1, W2, bm, xb, W1t, W2t, es1);
    k_gemm1      <<<dim3(32, 4, 4), 256, 0, stream>>>(xb, W1t, a1, h1t, es1, ed1);
    k_attn1      <<<dim3(16, 4, 4), 512, 0, stream>>>(h1t, es1, ed1, bmb, C1p, l1p);
    k_reduce_h2w <<<dim3(512),      256, 0, stream>>>(C1p, l1p, W2t, a2, h2wt, es2, ed2);
    k_attn2      <<<dim3(64, 8),    256, 0, stream>>>(h2wt, es2, ed2, bmb, out2p, l2p);
    k_final      <<<dim3(256),      256, 0, stream>>>(out2p, l2p, out);
}

// Round 9
// 222.708 us; speedup vs baseline: 2.6814x; 1.7819x over previous
//
#include <hip/hip_runtime.h>
#include <stdint.h>

#define N_NODES 4096
#define F_IN    512
#define F_HID   256
#define F_CLS   16
#define NHEAD   4
#define ALPHA   0.2f
#define LOG2E   1.4426950408889634f

typedef __attribute__((ext_vector_type(8))) short short8;
typedef __attribute__((ext_vector_type(4))) float f32x4;

__device__ __forceinline__ float bf2f(unsigned short h) {
    unsigned u = ((unsigned)h) << 16; float f; __builtin_memcpy(&f, &u, 4); return f;
}
__device__ __forceinline__ unsigned short f2bf(float f) {
    unsigned u; __builtin_memcpy(&u, &f, 4);
    u += 0x7fffu + ((u >> 16) & 1u);
    return (unsigned short)(u >> 16);
}
__device__ __forceinline__ float lo_bf(unsigned u) { u <<= 16;          float f; __builtin_memcpy(&f,&u,4); return f; }
__device__ __forceinline__ float hi_bf(unsigned u) { u &= 0xffff0000u;  float f; __builtin_memcpy(&f,&u,4); return f; }

__device__ __forceinline__ void async_cp16(void* lds, const void* g) {
    __builtin_amdgcn_global_load_lds(
        (const __attribute__((address_space(1))) unsigned int*)g,
        (__attribute__((address_space(3))) unsigned int*)lds,
        16, 0, 0);
}

// s_waitcnt imm: vmcnt[3:0], expcnt[6:4]=7 (nowait), lgkmcnt[11:8]
__device__ __forceinline__ void pipe_barrier_vm3() {
    __builtin_amdgcn_sched_barrier(0);
    __builtin_amdgcn_s_waitcnt(0x0073);   // vmcnt(3) lgkmcnt(0)
    __builtin_amdgcn_s_barrier();
    __builtin_amdgcn_sched_barrier(0);
}
__device__ __forceinline__ void pipe_barrier_vm4() {
    __builtin_amdgcn_sched_barrier(0);
    __builtin_amdgcn_s_waitcnt(0x0074);   // vmcnt(4) lgkmcnt(0)
    __builtin_amdgcn_s_barrier();
    __builtin_amdgcn_sched_barrier(0);
}

// ============ K1: fused prep: adj->bitmask | fp32->bf16 converts | zero es1/ed1 ============
#define PREP_BM_BLOCKS   16384
#define PREP_CV_BLOCKS   1296
#define PREP_Z_BLOCKS    4
__global__ __launch_bounds__(256) void k_prep(const int* __restrict__ adj,
                                              const float* __restrict__ x,
                                              const float* __restrict__ W1,
                                              const float* __restrict__ W2,
                                              unsigned long long* __restrict__ bm,
                                              unsigned short* __restrict__ xb,
                                              unsigned short* __restrict__ W1t,
                                              float* __restrict__ W2t,
                                              float* __restrict__ ez) {
    int b = blockIdx.x;
    if (b < PREP_BM_BLOCKS) {
        int wv = threadIdx.x >> 6, lane = threadIdx.x & 63;
        int idx0 = b * 1024 + wv * 256;
        const int* p = adj + idx0 + lane;
        unsigned long long m0 = __ballot(p[0]   > 0);
        unsigned long long m1 = __ballot(p[64]  > 0);
        unsigned long long m2 = __ballot(p[128] > 0);
        unsigned long long m3 = __ballot(p[192] > 0);
        if (lane == 0) {
            int w = idx0 >> 6;
            bm[w] = m0; bm[w+1] = m1; bm[w+2] = m2; bm[w+3] = m3;
        }
        return;
    }
    if (b < PREP_BM_BLOCKS + PREP_CV_BLOCKS) {
        int tid = (b - PREP_BM_BLOCKS) * 256 + threadIdx.x;
        const int NXV = (N_NODES * F_IN) / 8;       // 262144
        const int NW1 = NHEAD * 64 * F_HID;         // 65536
        if (tid < NXV) {
            float4 a = *(const float4*)&x[tid * 8];
            float4 c = *(const float4*)&x[tid * 8 + 4];
            uint4 w;
            w.x = (unsigned)f2bf(a.x) | ((unsigned)f2bf(a.y) << 16);
            w.y = (unsigned)f2bf(a.z) | ((unsigned)f2bf(a.w) << 16);
            w.z = (unsigned)f2bf(c.x) | ((unsigned)f2bf(c.y) << 16);
            w.w = (unsigned)f2bf(c.z) | ((unsigned)f2bf(c.w) << 16);
            *(uint4*)&xb[tid * 8] = w;
        } else if (tid < NXV + NW1) {
            int j = tid - NXV;
            int o = j & 255, f8 = (j >> 8) & 63, h = j >> 14;
            float v[8];
            #pragma unroll
            for (int k = 0; k < 8; ++k)
                v[k] = W1[(size_t)(h * F_IN + f8 * 8 + k) * F_HID + o];
            uint4 w;
            w.x = (unsigned)f2bf(v[0]) | ((unsigned)f2bf(v[1]) << 16);
            w.y = (unsigned)f2bf(v[2]) | ((unsigned)f2bf(v[3]) << 16);
            w.z = (unsigned)f2bf(v[4]) | ((unsigned)f2bf(v[5]) << 16);
            w.w = (unsigned)f2bf(v[6]) | ((unsigned)f2bf(v[7]) << 16);
            *(uint4*)&W1t[(size_t)(h * F_HID + o) * F_IN + f8 * 8] = w;
        } else {
            int j = tid - NXV - NW1;
            if (j < F_HID * F_CLS) {
                int o = j >> 4, c = j & 15;
                W2t[c * F_HID + o] = W2[j];
            }
        }
        return;
    }
    {
        int zb = b - PREP_BM_BLOCKS - PREP_CV_BLOCKS;
        float4* z4 = (float4*)ez;
        #pragma unroll
        for (int r = 0; r < 8; ++r)
            z4[zb * 2048 + r * 256 + threadIdx.x] = make_float4(0.f, 0.f, 0.f, 0.f);
    }
}

// ============ K2: h1t[h][o][n] GEMM + fused e1 — triple-buffer pipeline ============
__global__ __launch_bounds__(256, 4) void k_gemm1(const unsigned short* __restrict__ xb,
                                                  const unsigned short* __restrict__ W1t,
                                                  const float* __restrict__ a1,
                                                  unsigned short* __restrict__ h1t,
                                                  float* __restrict__ es1,
                                                  float* __restrict__ ed1) {
    __shared__ unsigned short Sld[3][6144];
    const int t = threadIdx.x;
    const int lane = t & 63, wv = t >> 6, quad = lane >> 4, l15 = lane & 15;
    const int wn = wv & 1, wo = wv >> 1;
    const int n0 = blockIdx.x * 128;
    const int oo0 = blockIdx.y * 64;
    const int h = blockIdx.z;
    const int kl = (lane >> 4) * 8;

    const unsigned short* gs[3];
    int loff[3];
    #pragma unroll
    for (int s = 0; s < 3; ++s) {
        int c = wv * 3 + s;
        loff[s] = c * 512;
        gs[s] = (c < 8)
            ? (xb  + (size_t)(n0 + c * 16 + l15) * F_IN + kl)
            : (W1t + (size_t)(h * F_HID + oo0 + (c - 8) * 16 + l15) * F_IN + kl);
    }
    #pragma unroll
    for (int s = 0; s < 3; ++s) async_cp16(&Sld[0][loff[s]], gs[s]);
    #pragma unroll
    for (int s = 0; s < 3; ++s) async_cp16(&Sld[1][loff[s]], gs[s] + 32);

    f32x4 acc[4][2] = {};
    int cur = 0;
    for (int it = 0; it < 16; ++it) {
        pipe_barrier_vm3();
        {
            const int nxt = (cur >= 1) ? cur - 1 : 2;
            const int off = ((it + 2) & 15) * 32;
            #pragma unroll
            for (int s = 0; s < 3; ++s) async_cp16(&Sld[nxt][loff[s]], gs[s] + off);
        }
        short8 bfw[2];
        #pragma unroll
        for (int mi = 0; mi < 2; ++mi)
            bfw[mi] = *(const short8*)&Sld[cur][(8 + wo * 2 + mi) * 512 + lane * 8];
        #pragma unroll
        for (int ni = 0; ni < 4; ++ni) {
            short8 af = *(const short8*)&Sld[cur][(wn * 4 + ni) * 512 + lane * 8];
            #pragma unroll
            for (int mi = 0; mi < 2; ++mi)
                acc[ni][mi] = __builtin_amdgcn_mfma_f32_16x16x32_bf16(af, bfw[mi], acc[ni][mi], 0, 0, 0);
        }
        cur = (cur == 2) ? 0 : cur + 1;
    }
    #pragma unroll
    for (int ni = 0; ni < 4; ++ni)
      #pragma unroll
      for (int mi = 0; mi < 2; ++mi) {
        int o = oo0 + wo * 32 + mi * 16 + l15;
        int nb = n0 + wn * 64 + ni * 16 + quad * 4;
        uint2 uu;
        uu.x = (unsigned)f2bf(acc[ni][mi][0]) | ((unsigned)f2bf(acc[ni][mi][1]) << 16);
        uu.y = (unsigned)f2bf(acc[ni][mi][2]) | ((unsigned)f2bf(acc[ni][mi][3]) << 16);
        *(uint2*)&h1t[(size_t)(h * F_HID + o) * N_NODES + nb] = uu;
      }
    float a1s[2], a1d[2];
    #pragma unroll
    for (int mi = 0; mi < 2; ++mi) {
        int o = oo0 + wo * 32 + mi * 16 + l15;
        a1s[mi] = a1[h * 2 * F_HID + o] * LOG2E;
        a1d[mi] = a1[h * 2 * F_HID + F_HID + o] * LOG2E;
    }
    #pragma unroll
    for (int ni = 0; ni < 4; ++ni) {
        #pragma unroll
        for (int rg = 0; rg < 4; ++rg) {
            float es = acc[ni][0][rg] * a1s[0] + acc[ni][1][rg] * a1s[1];
            float ed = acc[ni][0][rg] * a1d[0] + acc[ni][1][rg] * a1d[1];
            #pragma unroll
            for (int off = 1; off < 16; off <<= 1) {
                es += __shfl_xor(es, off, 64);
                ed += __shfl_xor(ed, off, 64);
            }
            if (l15 == 0) {
                int n = n0 + wn * 64 + ni * 16 + quad * 4 + rg;
                atomicAdd(&es1[h * N_NODES + n], es);
                atomicAdd(&ed1[h * N_NODES + n], ed);
            }
        }
    }
}

// ============ K3: fused masked-softmax-GEMM layer 1 — BK=64 stages ============
// Round-5 operand pattern exactly (inline ed float4 + per-iter ubyte bitmask — the
// VGPR=100 no-spill config). Structural delta: 64 j per pipeline stage => 2 sub-iters
// per barrier, 16 barriers total (was 32). LDS 3 x 32 KB = 96 KB. vmcnt(4) = 4 DMA/wave/stage.
__global__ __launch_bounds__(512, 2) void k_attn1(const unsigned short* __restrict__ h1t,
                                                  const float* __restrict__ es1,
                                                  const float* __restrict__ ed1,
                                                  const unsigned char* __restrict__ bmb,
                                                  unsigned short* __restrict__ C1p,
                                                  float* __restrict__ l1p) {
    __shared__ unsigned short Bld[3][16384];   // stage: [jh*8192 + ot*512 + lane*8]
    const int t = threadIdx.x;
    const int lane = t & 63, wv = t >> 6, quad = lane >> 4, l15 = lane & 15;
    const int m0 = blockIdx.x * 256;
    const int h = blockIdx.y;
    const int kz = blockIdx.z;
    const int mb0 = kz * 1024;

    const int m_r0 = m0 + wv * 32 + l15;
    const int m_r1 = m_r0 + 16;
    const float esr0 = es1[h * N_NODES + m_r0];   // pre-scaled by log2e
    const float esr1 = es1[h * N_NODES + m_r1];
    const unsigned char* bp0 = bmb + (size_t)m_r0 * (N_NODES / 8) + (mb0 >> 3);
    const unsigned char* bp1 = bmb + (size_t)m_r1 * (N_NODES / 8) + (mb0 >> 3);
    const float* edb = ed1 + h * N_NODES + mb0;

    // frag-order global bases; wave stages ot=wv and wv+8, both 32-j halves of each stage
    const unsigned short* gb0 = h1t + (size_t)(h * F_HID + wv * 16 + l15) * N_NODES + mb0 + quad * 8;
    const unsigned short* gb1 = h1t + (size_t)(h * F_HID + (wv + 8) * 16 + l15) * N_NODES + mb0 + quad * 8;
    // prologue: stages 0,1
    #pragma unroll
    for (int st = 0; st < 2; ++st) {
        async_cp16(&Bld[st][wv * 512],              gb0 + st * 64);
        async_cp16(&Bld[st][(wv + 8) * 512],        gb1 + st * 64);
        async_cp16(&Bld[st][8192 + wv * 512],       gb0 + st * 64 + 32);
        async_cp16(&Bld[st][8192 + (wv + 8) * 512], gb1 + st * 64 + 32);
    }

    f32x4 acc[16][2] = {};
    float lsum0 = 0.f, lsum1 = 0.f;
    int cur = 0;
    for (int p = 0; p < 16; ++p) {
        pipe_barrier_vm4();
        {   // DMA prefetch stage p+2 (wrapped tail — dead data, never read)
            const int nxt = (cur >= 1) ? cur - 1 : 2;
            const int joff = ((p + 2) & 15) * 64;
            async_cp16(&Bld[nxt][wv * 512],              gb0 + joff);
            async_cp16(&Bld[nxt][(wv + 8) * 512],        gb1 + joff);
            async_cp16(&Bld[nxt][8192 + wv * 512],       gb0 + joff + 32);
            async_cp16(&Bld[nxt][8192 + (wv + 8) * 512], gb1 + joff + 32);
        }
        #pragma unroll
        for (int jh = 0; jh < 2; ++jh) {
            const int mb = p * 64 + jh * 32;
            float4 e0 = *(const float4*)&edb[mb + quad * 8];
            float4 e1v = *(const float4*)&edb[mb + quad * 8 + 4];
            float ev[8] = {e0.x, e0.y, e0.z, e0.w, e1v.x, e1v.y, e1v.z, e1v.w};
            unsigned bb0 = bp0[(mb >> 3) + quad];
            unsigned bb1 = bp1[(mb >> 3) + quad];
            unsigned up0[8], up1[8];
            #pragma unroll
            for (int j = 0; j < 8; ++j) {
                float s0 = esr0 + ev[j]; s0 = fmaxf(s0, ALPHA * s0);
                float p0 = ((bb0 >> j) & 1u) ? __builtin_amdgcn_exp2f(s0) : 0.f;
                unsigned u0; __builtin_memcpy(&u0, &p0, 4); u0 &= 0xffff0000u;
                float pt0; __builtin_memcpy(&pt0, &u0, 4);
                lsum0 += pt0; up0[j] = u0;
                float s1 = esr1 + ev[j]; s1 = fmaxf(s1, ALPHA * s1);
                float p1 = ((bb1 >> j) & 1u) ? __builtin_amdgcn_exp2f(s1) : 0.f;
                unsigned u1; __builtin_memcpy(&u1, &p1, 4); u1 &= 0xffff0000u;
                float pt1; __builtin_memcpy(&pt1, &u1, 4);
                lsum1 += pt1; up1[j] = u1;
            }
            int pk0[4], pk1[4];
            #pragma unroll
            for (int j = 0; j < 4; ++j) {
                pk0[j] = __builtin_amdgcn_perm(up0[2*j+1], up0[2*j], 0x07060302u);
                pk1[j] = __builtin_amdgcn_perm(up1[2*j+1], up1[2*j], 0x07060302u);
            }
            short8 bfrag0, bfrag1;
            __builtin_memcpy(&bfrag0, pk0, 16);
            __builtin_memcpy(&bfrag1, pk1, 16);
            #pragma unroll
            for (int ot = 0; ot < 16; ++ot) {
                short8 af = *(const short8*)&Bld[cur][jh * 8192 + ot * 512 + lane * 8];
                acc[ot][0] = __builtin_amdgcn_mfma_f32_16x16x32_bf16(af, bfrag0, acc[ot][0], 0, 0, 0);
                acc[ot][1] = __builtin_amdgcn_mfma_f32_16x16x32_bf16(af, bfrag1, acc[ot][1], 0, 0, 0);
            }
        }
        cur = (cur == 2) ? 0 : cur + 1;
    }
    lsum0 += __shfl_xor(lsum0, 16, 64); lsum0 += __shfl_xor(lsum0, 32, 64);
    lsum1 += __shfl_xor(lsum1, 16, 64); lsum1 += __shfl_xor(lsum1, 32, 64);
    if (quad == 0) {
        l1p[(size_t)(kz * NHEAD + h) * N_NODES + m_r0] = lsum0;
        l1p[(size_t)(kz * NHEAD + h) * N_NODES + m_r1] = lsum1;
    }
    unsigned short* Cb = C1p + (size_t)(kz * NHEAD + h) * N_NODES * F_HID;
    #pragma unroll
    for (int ot = 0; ot < 16; ++ot)
      #pragma unroll
      for (int mi = 0; mi < 2; ++mi) {
        int m = (mi == 0) ? m_r0 : m_r1;
        int o0 = ot * 16 + quad * 4;
        uint2 uu;
        uu.x = (unsigned)f2bf(acc[ot][mi][0]) | ((unsigned)f2bf(acc[ot][mi][1]) << 16);
        uu.y = (unsigned)f2bf(acc[ot][mi][2]) | ((unsigned)f2bf(acc[ot][mi][3]) << 16);
        *(uint2*)&Cb[(size_t)m * F_HID + o0] = uu;
      }
}

// ============ K4: FUSED reduce1 + h2w: C1p -> h2 (LDS only) -> h2wt, es2, ed2 ============
__global__ __launch_bounds__(256) void k_reduce_h2w(const unsigned short* __restrict__ C1p,
                                                    const float* __restrict__ l1p,
                                                    const float* __restrict__ W2t,
                                                    const float* __restrict__ a2,
                                                    unsigned short* __restrict__ h2wt,
                                                    float* __restrict__ es2,
                                                    float* __restrict__ ed2) {
    __shared__ float h2s[8][256];
    int t = threadIdx.x;
    int og = t & 31, nl = t >> 5;
    int n = blockIdx.x * 8 + nl;
    float acc8[8] = {};
    #pragma unroll
    for (int h = 0; h < NHEAD; ++h) {
        float den = 0.f, num[8] = {};
        #pragma unroll
        for (int kz = 0; kz < 4; ++kz) {
            den += l1p[(size_t)(kz * NHEAD + h) * N_NODES + n];
            uint4 u = *(const uint4*)&C1p[((size_t)(kz * NHEAD + h) * N_NODES + n) * F_HID + og * 8];
            num[0] += lo_bf(u.x); num[1] += hi_bf(u.x);
            num[2] += lo_bf(u.y); num[3] += hi_bf(u.y);
            num[4] += lo_bf(u.z); num[5] += hi_bf(u.z);
            num[6] += lo_bf(u.w); num[7] += hi_bf(u.w);
        }
        float rinv = 1.f / fmaxf(den, 1e-30f);
        #pragma unroll
        for (int j = 0; j < 8; ++j) acc8[j] += num[j] * rinv;
    }
    #pragma unroll
    for (int j = 0; j < 8; ++j) {
        float v = fmaxf(acc8[j] * 0.25f, 0.f);
        h2s[nl][og * 8 + j] = bf2f(f2bf(v));
    }
    __syncthreads();
    if (t < 128) {
        int c = t & 15, n2l = t >> 4;
        int n2 = blockIdx.x * 8 + n2l;
        const float* wrow = W2t + c * F_HID;
        const float* hrow = h2s[n2l];
        float dot = 0.f;
        #pragma unroll 4
        for (int o = 0; o < F_HID; o += 8) {
            float4 hv0 = *(const float4*)&hrow[o];
            float4 hv1 = *(const float4*)&hrow[o + 4];
            float4 w0 = *(const float4*)&wrow[o];
            float4 w1 = *(const float4*)&wrow[o + 4];
            dot += hv0.x*w0.x + hv0.y*w0.y + hv0.z*w0.z + hv0.w*w0.w;
            dot += hv1.x*w1.x + hv1.y*w1.y + hv1.z*w1.z + hv1.w*w1.w;
        }
        h2wt[(size_t)c * N_NODES + n2] = f2bf(dot);
        float es = dot * a2[c] * LOG2E;
        float ed = dot * a2[F_CLS + c] * LOG2E;
        #pragma unroll
        for (int off = 1; off < 16; off <<= 1) {
            es += __shfl_xor(es, off, 64);
            ed += __shfl_xor(ed, off, 64);
        }
        if (c == 0) { es2[n2] = es; ed2[n2] = ed; }
    }
}

// ============ K5: layer-2 fused softmax-GEMM — simple, ksplit=8 ============
__global__ __launch_bounds__(256, 4) void k_attn2(const unsigned short* __restrict__ h2wt,
                                                  const float* __restrict__ es2,
                                                  const float* __restrict__ ed2,
                                                  const unsigned char* __restrict__ bmb,
                                                  float* __restrict__ out2p,
                                                  float* __restrict__ l2p) {
    const int t = threadIdx.x;
    const int lane = t & 63, wv = t >> 6, quad = lane >> 4, l15 = lane & 15;
    const int m0 = blockIdx.x * 64;
    const int ks = blockIdx.y;
    const int m_r = m0 + wv * 16 + l15;
    const float esr = es2[m_r];
    const unsigned char* bp = bmb + (size_t)m_r * (N_NODES / 8);

    f32x4 acc = {};
    float lsum = 0.f;
    for (int it = 0; it < 16; ++it) {
        const int mb = ks * 512 + it * 32;
        float4 e0 = *(const float4*)&ed2[mb + quad * 8];
        float4 e1v = *(const float4*)&ed2[mb + quad * 8 + 4];
        float ev[8] = {e0.x, e0.y, e0.z, e0.w, e1v.x, e1v.y, e1v.z, e1v.w};
        unsigned bb = bp[(mb >> 3) + quad];
        short8 afrag;
        #pragma unroll
        for (int j = 0; j < 8; ++j) {
            float s = esr + ev[j]; s = fmaxf(s, ALPHA * s);
            float p = ((bb >> j) & 1u) ? __builtin_amdgcn_exp2f(s) : 0.f;
            lsum += p; afrag[j] = (short)f2bf(p);
        }
        short8 bfr = *(const short8*)&h2wt[(size_t)l15 * N_NODES + mb + quad * 8];
        acc = __builtin_amdgcn_mfma_f32_16x16x32_bf16(afrag, bfr, acc, 0, 0, 0);
    }
    lsum += __shfl_xor(lsum, 16, 64); lsum += __shfl_xor(lsum, 32, 64);
    if (quad == 0) l2p[(size_t)ks * N_NODES + m_r] = lsum;
    #pragma unroll
    for (int rg = 0; rg < 4; ++rg) {
        int row = m0 + wv * 16 + quad * 4 + rg;
        out2p[((size_t)ks * N_NODES + row) * F_CLS + l15] = acc[rg];
    }
}

// ============ K6: combine ksplit, normalize, log_softmax -> fp32 ============
__global__ __launch_bounds__(256) void k_final(const float* __restrict__ out2p,
                                               const float* __restrict__ l2p,
                                               float* __restrict__ out) {
    int t = threadIdx.x;
    int c = t & 15, nl = t >> 4;
    int n = blockIdx.x * 16 + nl;
    float v = 0.f, l = 0.f;
    #pragma unroll
    for (int ks = 0; ks < 8; ++ks) {
        v += out2p[((size_t)ks * N_NODES + n) * F_CLS + c];
        l += l2p[(size_t)ks * N_NODES + n];
    }
    v /= fmaxf(l, 1e-30f);
    float mx = v;
    #pragma unroll
    for (int off = 1; off < 16; off <<= 1) mx = fmaxf(mx, __shfl_xor(mx, off, 64));
    float e = __expf(v - mx);
    float se = e;
    #pragma unroll
    for (int off = 1; off < 16; off <<= 1) se += __shfl_xor(se, off, 64);
    out[(size_t)n * F_CLS + c] = v - mx - __logf(se);
}

// ---------------- workspace layout (bytes) ----------------
#define OFF_BM    0ull                      // 2 MB   bitmask
#define OFF_XB    2097152ull                // 4 MB   x bf16
#define OFF_W1T   6291456ull                // 1 MB   W1t bf16
#define OFF_W2T   7340032ull                // 16 KB  W2t fp32
#define OFF_ES1   7356416ull                // 64 KB  (zeroed with ED1 in k_prep)
#define OFF_ED1   7421952ull                // 64 KB
#define OFF_ES2   7487488ull                // 16 KB
#define OFF_ED2   7503872ull                // 16 KB
#define OFF_L1P   7520256ull                // 256 KB [kz][h][n]
#define OFF_L2P   7782400ull                // 128 KB [ks][n]
#define OFF_OUT2P 7910400ull                // 2 MB   fp32 [ks][n][c]
#define OFF_H2WT  10007552ull               // 128 KB bf16
#define OFF_H1T   10138624ull               // 8 MB   [h][o][n] bf16
#define OFF_C1P   18527232ull               // 16 MB  bf16 [kz][h][m][o]

extern "C" void kernel_launch(void* const* d_in, const int* in_sizes, int n_in,
                              void* d_out, int out_size, void* d_ws, size_t ws_size,
                              hipStream_t stream) {
    const float* x   = (const float*)d_in[0];
    const int*   adj = (const int*)d_in[1];
    const float* W1  = (const float*)d_in[2];
    const float* a1  = (const float*)d_in[3];
    const float* W2  = (const float*)d_in[4];
    const float* a2  = (const float*)d_in[5];
    float* out = (float*)d_out;
    char* ws = (char*)d_ws;

    unsigned long long* bm  = (unsigned long long*)(ws + OFF_BM);
    unsigned char*      bmb = (unsigned char*)(ws + OFF_BM);
    unsigned short* xb   = (unsigned short*)(ws + OFF_XB);
    unsigned short* W1t  = (unsigned short*)(ws + OFF_W1T);
    float* W2t   = (float*)(ws + OFF_W2T);
    float* es1   = (float*)(ws + OFF_ES1);
    float* ed1   = (float*)(ws + OFF_ED1);
    float* es2   = (float*)(ws + OFF_ES2);
    float* ed2   = (float*)(ws + OFF_ED2);
    float* l1p   = (float*)(ws + OFF_L1P);
    float* l2p   = (float*)(ws + OFF_L2P);
    float* out2p = (float*)(ws + OFF_OUT2P);
    unsigned short* h2wt = (unsigned short*)(ws + OFF_H2WT);
    unsigned short* h1t  = (unsigned short*)(ws + OFF_H1T);
    unsigned short* C1p  = (unsigned short*)(ws + OFF_C1P);

    k_prep       <<<dim3(PREP_BM_BLOCKS + PREP_CV_BLOCKS + PREP_Z_BLOCKS), 256, 0, stream>>>(
                     adj, x, W1, W2, bm, xb, W1t, W2t, es1);
    k_gemm1      <<<dim3(32, 4, 4), 256, 0, stream>>>(xb, W1t, a1, h1t, es1, ed1);
    k_attn1      <<<dim3(16, 4, 4), 512, 0, stream>>>(h1t, es1, ed1, bmb, C1p, l1p);
    k_reduce_h2w <<<dim3(512),      256, 0, stream>>>(C1p, l1p, W2t, a2, h2wt, es2, ed2);
    k_attn2      <<<dim3(64, 8),    256, 0, stream>>>(h2wt, es2, ed2, bmb, out2p, l2p);
    k_final      <<<dim3(256),      256, 0, stream>>>(out2p, l2p, out);
}